// Round 1
// baseline (1133.476 us; speedup 1.0000x reference)
//
#include <hip/hip_runtime.h>
#include <math.h>

#define BN_EPS 1e-5f

// ---------------- preprocessing: CSR by dst ----------------
__global__ void k_count(const int* __restrict__ ei, int E, int N, int* __restrict__ deg){
  int e = blockIdx.x*256 + threadIdx.x;
  int ET = E + N;
  if (e >= ET) return;
  int dst = (e < E) ? ei[E + e] : (e - E);   // self loops appended
  atomicAdd(&deg[dst], 1);
}

__global__ __launch_bounds__(1024) void k_scan_block(const int* __restrict__ deg, int* __restrict__ offs,
                                                     int* __restrict__ part, int N){
  __shared__ int sh[1024];
  int t = threadIdx.x; int i = blockIdx.x*1024 + t;
  int v = (i < N) ? deg[i] : 0;
  sh[t] = v; __syncthreads();
  for (int off = 1; off < 1024; off <<= 1){
    int u = (t >= off) ? sh[t - off] : 0;
    __syncthreads();
    sh[t] += u;
    __syncthreads();
  }
  if (i < N) offs[i] = sh[t] - v;            // exclusive
  if (t == 1023) part[blockIdx.x] = sh[1023];
}

__global__ void k_scan_part(int* part, int nb){
  if (threadIdx.x == 0 && blockIdx.x == 0){
    int s = 0;
    for (int i = 0; i < nb; ++i){ int v = part[i]; part[i] = s; s += v; }
  }
}

__global__ void k_add_part(int* __restrict__ offs, const int* __restrict__ part, int N){
  int i = blockIdx.x*256 + threadIdx.x;
  if (i < N) offs[i] += part[i >> 10];
}

__global__ void k_fill(const int* __restrict__ ei, int E, int N, const int* __restrict__ offs,
                       int* __restrict__ cursor, int* __restrict__ csr){
  int e = blockIdx.x*256 + threadIdx.x; int ET = E + N;
  if (e >= ET) return;
  int src, dst;
  if (e < E){ src = ei[e]; dst = ei[E + e]; } else { src = e - E; dst = src; }
  int pos = offs[dst] + atomicAdd(&cursor[dst], 1);
  csr[pos] = src;
}

// ---------------- f32 GEMM: C[M x 128] = A[M x 128] @ W[128 x 128], optional row scale rsqrt(deg) ----------------
#define TM 64
__global__ __launch_bounds__(256) void k_gemm128(const float* __restrict__ A, const float* __restrict__ W,
                                                 float* __restrict__ C, int M, const int* __restrict__ deg){
  __shared__ float As[TM][128];
  __shared__ float Ws[128][128];
  int tid = threadIdx.x;
  int row0 = blockIdx.x * TM;
  {
    const float4* Wv = (const float4*)W;
    float4* Wsv = (float4*)&Ws[0][0];
    for (int i = tid; i < 128*32; i += 256) Wsv[i] = Wv[i];
  }
  for (int i = tid; i < TM*32; i += 256){
    int r = i >> 5, c4 = i & 31; int gr = row0 + r;
    float4 v = (gr < M) ? ((const float4*)A)[(size_t)gr*32 + c4] : make_float4(0.f,0.f,0.f,0.f);
    ((float4*)&As[r][0])[c4] = v;
  }
  __syncthreads();
  int ty = tid >> 4, tx = tid & 15;
  int r0 = ty * 4, c0 = tx * 8;
  float acc[4][8] = {};
  #pragma unroll 4
  for (int k = 0; k < 128; ++k){
    float a0 = As[r0][k], a1 = As[r0+1][k], a2 = As[r0+2][k], a3 = As[r0+3][k];
    float4 w0 = *(const float4*)&Ws[k][c0];
    float4 w1 = *(const float4*)&Ws[k][c0+4];
    float wv[8] = {w0.x,w0.y,w0.z,w0.w,w1.x,w1.y,w1.z,w1.w};
    #pragma unroll
    for (int j = 0; j < 8; ++j){
      acc[0][j] += a0*wv[j];
      acc[1][j] += a1*wv[j];
      acc[2][j] += a2*wv[j];
      acc[3][j] += a3*wv[j];
    }
  }
  #pragma unroll
  for (int i2 = 0; i2 < 4; ++i2){
    int gr = row0 + r0 + i2;
    if (gr >= M) continue;
    float sc = deg ? rsqrtf((float)deg[gr]) : 1.0f;
    float4 o0 = make_float4(acc[i2][0]*sc, acc[i2][1]*sc, acc[i2][2]*sc, acc[i2][3]*sc);
    float4 o1 = make_float4(acc[i2][4]*sc, acc[i2][5]*sc, acc[i2][6]*sc, acc[i2][7]*sc);
    float4* Cp = (float4*)&C[(size_t)gr*128];
    Cp[tx*2] = o0; Cp[tx*2 + 1] = o1;
  }
}

// ---------------- GAT: per-node attention logits (a_src, a_dst) ----------------
__global__ __launch_bounds__(256) void k_attn(const float* __restrict__ Y, const float* __restrict__ asrcw,
                                              const float* __restrict__ adstw,
                                              float* __restrict__ a_src, float* __restrict__ a_dst, int N){
  int n = (blockIdx.x*256 + threadIdx.x) >> 6;
  int lane = threadIdx.x & 63;
  if (n >= N) return;
  int head = lane >> 4;
  int d0 = (lane & 15) * 2;
  float2 hv = ((const float2*)Y)[(size_t)n*64 + lane];
  float vs = hv.x * asrcw[head*32 + d0] + hv.y * asrcw[head*32 + d0 + 1];
  float vd = hv.x * adstw[head*32 + d0] + hv.y * adstw[head*32 + d0 + 1];
  #pragma unroll
  for (int m = 1; m < 16; m <<= 1){
    vs += __shfl_xor(vs, m, 64);
    vd += __shfl_xor(vd, m, 64);
  }
  if ((lane & 15) == 0){
    a_src[n*4 + head] = vs;
    a_dst[n*4 + head] = vd;
  }
}

// ---------------- GAT aggregation: online softmax over incoming edges, wave per node ----------------
__global__ __launch_bounds__(256) void k_gat_agg(const float* __restrict__ Y, const int* __restrict__ csr,
                                                 const int* __restrict__ offs, const int* __restrict__ deg,
                                                 const float* __restrict__ a_src, const float* __restrict__ a_dst,
                                                 const float* __restrict__ bias, float* __restrict__ out, int N){
  int n = (blockIdx.x*256 + threadIdx.x) >> 6;
  int lane = threadIdx.x & 63;
  if (n >= N) return;
  int head = lane >> 4;
  float adn = a_dst[n*4 + head];
  int beg = offs[n], d = deg[n];
  float m = -INFINITY, s = 0.f, accx = 0.f, accy = 0.f;
  const float2* Yv = (const float2*)Y;
  int i = 0;
  for (; i + 4 <= d; i += 4){
    int s0 = csr[beg+i], s1 = csr[beg+i+1], s2 = csr[beg+i+2], s3 = csr[beg+i+3];
    float e0 = a_src[s0*4+head], e1 = a_src[s1*4+head], e2 = a_src[s2*4+head], e3 = a_src[s3*4+head];
    float2 v0 = Yv[(size_t)s0*64+lane], v1 = Yv[(size_t)s1*64+lane],
           v2 = Yv[(size_t)s2*64+lane], v3 = Yv[(size_t)s3*64+lane];
    float ee[4] = {e0+adn, e1+adn, e2+adn, e3+adn};
    float2 vv[4] = {v0, v1, v2, v3};
    #pragma unroll
    for (int j = 0; j < 4; ++j){
      float e = ee[j]; e = e > 0.f ? e : 0.2f*e;
      float mn = fmaxf(m, e);
      float corr = __expf(m - mn);
      float p = __expf(e - mn);
      s = s*corr + p;
      accx = accx*corr + p*vv[j].x;
      accy = accy*corr + p*vv[j].y;
      m = mn;
    }
  }
  for (; i < d; ++i){
    int sc = csr[beg+i];
    float e = a_src[sc*4+head] + adn;
    e = e > 0.f ? e : 0.2f*e;
    float mn = fmaxf(m, e);
    float corr = __expf(m - mn);
    float p = __expf(e - mn);
    float2 v = Yv[(size_t)sc*64 + lane];
    s = s*corr + p;
    accx = accx*corr + p*v.x;
    accy = accy*corr + p*v.y;
    m = mn;
  }
  float inv = 1.f / s;
  float2 b = ((const float2*)bias)[lane];
  float z0 = accx*inv + b.x, z1 = accy*inv + b.y;
  z0 = z0 > 0.f ? z0 : expm1f(z0);
  z1 = z1 > 0.f ? z1 : expm1f(z1);
  ((float2*)out)[(size_t)n*64 + lane] = make_float2(z0, z1);
}

// ---------------- GCN aggregation + folded BN + ELU + residual, wave per node ----------------
__global__ __launch_bounds__(256) void k_gcn_agg(const float* __restrict__ Y, const float* __restrict__ resid,
                                                 float* __restrict__ out, const int* __restrict__ csr,
                                                 const int* __restrict__ offs, const int* __restrict__ deg,
                                                 const float* __restrict__ gb, const float* __restrict__ bg,
                                                 const float* __restrict__ bb, const float* __restrict__ bm,
                                                 const float* __restrict__ bv, int N){
  int n = (blockIdx.x*256 + threadIdx.x) >> 6;
  int lane = threadIdx.x & 63;
  if (n >= N) return;
  int beg = offs[n], d = deg[n];
  float ax = 0.f, ay = 0.f;
  const float2* Yv = (const float2*)Y;
  int i = 0;
  for (; i + 4 <= d; i += 4){
    int s0 = csr[beg+i], s1 = csr[beg+i+1], s2 = csr[beg+i+2], s3 = csr[beg+i+3];
    float2 v0 = Yv[(size_t)s0*64+lane], v1 = Yv[(size_t)s1*64+lane],
           v2 = Yv[(size_t)s2*64+lane], v3 = Yv[(size_t)s3*64+lane];
    ax += v0.x + v1.x + v2.x + v3.x;
    ay += v0.y + v1.y + v2.y + v3.y;
  }
  for (; i < d; ++i){
    int sc = csr[beg+i];
    float2 v = Yv[(size_t)sc*64 + lane];
    ax += v.x; ay += v.y;
  }
  float dinv = rsqrtf((float)d);
  float2 g  = ((const float2*)bg)[lane];
  float2 b  = ((const float2*)bb)[lane];
  float2 mm = ((const float2*)bm)[lane];
  float2 vv = ((const float2*)bv)[lane];
  float2 gb2 = ((const float2*)gb)[lane];
  float A0 = g.x * rsqrtf(vv.x + BN_EPS), A1 = g.y * rsqrtf(vv.y + BN_EPS);
  float z0 = ax*dinv*A0 + (gb2.x - mm.x)*A0 + b.x;
  float z1 = ay*dinv*A1 + (gb2.y - mm.y)*A1 + b.y;
  z0 = z0 > 0.f ? z0 : expm1f(z0);
  z1 = z1 > 0.f ? z1 : expm1f(z1);
  if (resid){
    float2 r = ((const float2*)resid)[(size_t)n*64 + lane];
    z0 += r.x; z1 += r.y;
  }
  ((float2*)out)[(size_t)n*64 + lane] = make_float2(z0, z1);
}

// ---------------- mean pool per graph (batch sorted) ----------------
__global__ __launch_bounds__(128) void k_pool(const float* __restrict__ H, const int* __restrict__ batch,
                                              float* __restrict__ G, int N){
  int gid = blockIdx.x; int c = threadIdx.x;
  int lo = 0, hi = N;
  while (lo < hi){ int mid = (lo + hi) >> 1; if (batch[mid] < gid) lo = mid + 1; else hi = mid; }
  int start = lo;
  lo = start; hi = N;
  while (lo < hi){ int mid = (lo + hi) >> 1; if (batch[mid] < gid + 1) lo = mid + 1; else hi = mid; }
  int end = lo;
  float acc = 0.f;
  for (int r = start; r < end; ++r) acc += H[(size_t)r*128 + c];
  float cnt = (float)(end - start);
  G[gid*128 + c] = acc / fmaxf(cnt, 1.0f);
}

// ---------------- MLP head: elu(g@p1+b1) @ p2 + b2 -> emb; emb @ cls + b -> out ----------------
__global__ __launch_bounds__(128) void k_mlp(const float* __restrict__ G, const float* __restrict__ p1w,
                                             const float* __restrict__ p1b, const float* __restrict__ p2w,
                                             const float* __restrict__ p2b, const float* __restrict__ cw,
                                             const float* __restrict__ cb, float* __restrict__ out, int NG){
  int gid = blockIdx.x; int t = threadIdx.x;
  __shared__ float gv[128], t1[128], e[64];
  gv[t] = G[gid*128 + t];
  __syncthreads();
  float acc = p1b[t];
  for (int k = 0; k < 128; ++k) acc += gv[k] * p1w[k*128 + t];
  t1[t] = acc > 0.f ? acc : expm1f(acc);
  __syncthreads();
  if (t < 64){
    float a = p2b[t];
    for (int k = 0; k < 128; ++k) a += t1[k] * p2w[k*64 + t];
    e[t] = a;
    out[NG*3 + gid*64 + t] = a;   // emb output
  }
  __syncthreads();
  if (t < 3){
    float a = cb[t];
    for (int k = 0; k < 64; ++k) a += e[k] * cw[k*3 + t];
    out[gid*3 + t] = a;           // logits output
  }
}

extern "C" void kernel_launch(void* const* d_in, const int* in_sizes, int n_in,
                              void* d_out, int out_size, void* d_ws, size_t ws_size,
                              hipStream_t stream){
  const float* x      = (const float*)d_in[0];
  const int*   ei     = (const int*)d_in[1];
  const int*   batch  = (const int*)d_in[3];
  const float* gat_w  = (const float*)d_in[4];
  const float* att_s  = (const float*)d_in[5];
  const float* att_d  = (const float*)d_in[6];
  const float* gat_b  = (const float*)d_in[7];
  const float* w1 = (const float*)d_in[8];  const float* b1 = (const float*)d_in[9];
  const float* bn1g = (const float*)d_in[10], *bn1b = (const float*)d_in[11],
             * bn1m = (const float*)d_in[12], *bn1v = (const float*)d_in[13];
  const float* w2 = (const float*)d_in[14]; const float* b2 = (const float*)d_in[15];
  const float* bn2g = (const float*)d_in[16], *bn2b = (const float*)d_in[17],
             * bn2m = (const float*)d_in[18], *bn2v = (const float*)d_in[19];
  const float* w3 = (const float*)d_in[20]; const float* b3 = (const float*)d_in[21];
  const float* bn3g = (const float*)d_in[22], *bn3b = (const float*)d_in[23],
             * bn3m = (const float*)d_in[24], *bn3v = (const float*)d_in[25];
  const float* p1w = (const float*)d_in[26]; const float* p1b = (const float*)d_in[27];
  const float* p2w = (const float*)d_in[28]; const float* p2b = (const float*)d_in[29];
  const float* cw  = (const float*)d_in[30]; const float* cb  = (const float*)d_in[31];

  int N  = in_sizes[3];
  int E  = in_sizes[1] / 2;
  int ET = E + N;
  int NG = out_size / 67;   // 1024 graphs (3 + 64 outputs each)

  char* ws = (char*)d_ws;
  size_t off = 0;
  auto alloc = [&](size_t bytes) -> void* {
    void* p = ws + off;
    off = (off + bytes + 255) & ~(size_t)255;
    return p;
  };
  float* A    = (float*)alloc((size_t)N * 128 * 4);
  float* B    = (float*)alloc((size_t)N * 128 * 4);
  float* Y    = (float*)alloc((size_t)N * 128 * 4);
  int*   csr  = (int*)alloc((size_t)ET * 4);
  int*   deg  = (int*)alloc((size_t)N * 4);
  int*   offs = (int*)alloc((size_t)N * 4);
  int*   curs = (int*)alloc((size_t)N * 4);
  int*   part = (int*)alloc(1024 * 4);
  float* asrc = (float*)alloc((size_t)N * 4 * 4);
  float* adst = (float*)alloc((size_t)N * 4 * 4);
  float* G    = (float*)alloc((size_t)NG * 128 * 4);

  hipMemsetAsync(deg,  0, (size_t)N * 4, stream);
  hipMemsetAsync(curs, 0, (size_t)N * 4, stream);

  int nb = (N + 1023) / 1024;
  k_count<<<(ET + 255)/256, 256, 0, stream>>>(ei, E, N, deg);
  k_scan_block<<<nb, 1024, 0, stream>>>(deg, offs, part, N);
  k_scan_part<<<1, 1, 0, stream>>>(part, nb);
  k_add_part<<<(N + 255)/256, 256, 0, stream>>>(offs, part, N);
  k_fill<<<(ET + 255)/256, 256, 0, stream>>>(ei, E, N, offs, curs, csr);

  int gblk = (N + TM - 1) / TM;
  int ablk = (N + 3) / 4;

  // GAT
  k_gemm128<<<gblk, 256, 0, stream>>>(x, gat_w, Y, N, nullptr);
  k_attn<<<ablk, 256, 0, stream>>>(Y, att_s, att_d, asrc, adst, N);
  k_gat_agg<<<ablk, 256, 0, stream>>>(Y, csr, offs, deg, asrc, adst, gat_b, A, N);

  // GCN 1 (residual A), out B
  k_gemm128<<<gblk, 256, 0, stream>>>(A, w1, Y, N, deg);
  k_gcn_agg<<<ablk, 256, 0, stream>>>(Y, A, B, csr, offs, deg, b1, bn1g, bn1b, bn1m, bn1v, N);
  // GCN 2 (residual B), out A
  k_gemm128<<<gblk, 256, 0, stream>>>(B, w2, Y, N, deg);
  k_gcn_agg<<<ablk, 256, 0, stream>>>(Y, B, A, csr, offs, deg, b2, bn2g, bn2b, bn2m, bn2v, N);
  // GCN 3 (no residual), out B
  k_gemm128<<<gblk, 256, 0, stream>>>(A, w3, Y, N, deg);
  k_gcn_agg<<<ablk, 256, 0, stream>>>(Y, nullptr, B, csr, offs, deg, b3, bn3g, bn3b, bn3m, bn3v, N);

  // pool + head
  k_pool<<<NG, 128, 0, stream>>>(B, batch, G, N);
  k_mlp<<<NG, 128, 0, stream>>>(G, p1w, p1b, p2w, p2b, cw, cb, (float*)d_out, NG);
}

// Round 2
// 1033.786 us; speedup vs baseline: 1.0964x; 1.0964x over previous
//
#include <hip/hip_runtime.h>
#include <math.h>

#define BN_EPS 1e-5f

// ---------- bf16 helpers ----------
__device__ inline unsigned bfpack2(float a, float b){
  unsigned ua = __float_as_uint(a); ua = (ua + 0x7fffu + ((ua >> 16) & 1u)) >> 16;
  unsigned ub = __float_as_uint(b); ub = (ub + 0x7fffu + ((ub >> 16) & 1u)) >> 16;
  return ua | (ub << 16);
}
__device__ inline float bflo(unsigned u){ return __uint_as_float(u << 16); }
__device__ inline float bfhi(unsigned u){ return __uint_as_float(u & 0xffff0000u); }

// ---------------- preprocessing: CSR by dst ----------------
__global__ void k_count(const int* __restrict__ ei, int E, int N, int* __restrict__ deg){
  int e = blockIdx.x*256 + threadIdx.x;
  int ET = E + N;
  if (e >= ET) return;
  int dst = (e < E) ? ei[E + e] : (e - E);   // self loops appended
  atomicAdd(&deg[dst], 1);
}

__global__ __launch_bounds__(1024) void k_scan_block(const int* __restrict__ deg, int* __restrict__ offs,
                                                     int* __restrict__ part, int N){
  __shared__ int sh[1024];
  int t = threadIdx.x; int i = blockIdx.x*1024 + t;
  int v = (i < N) ? deg[i] : 0;
  sh[t] = v; __syncthreads();
  for (int off = 1; off < 1024; off <<= 1){
    int u = (t >= off) ? sh[t - off] : 0;
    __syncthreads();
    sh[t] += u;
    __syncthreads();
  }
  if (i < N) offs[i] = sh[t] - v;            // exclusive
  if (t == 1023) part[blockIdx.x] = sh[1023];
}

__global__ void k_scan_part(int* part, int nb){
  if (threadIdx.x == 0 && blockIdx.x == 0){
    int s = 0;
    for (int i = 0; i < nb; ++i){ int v = part[i]; part[i] = s; s += v; }
  }
}

__global__ void k_add_part(int* __restrict__ offs, const int* __restrict__ part, int N){
  int i = blockIdx.x*256 + threadIdx.x;
  if (i < N) offs[i] += part[i >> 10];
}

__global__ void k_fill(const int* __restrict__ ei, int E, int N, const int* __restrict__ offs,
                       int* __restrict__ cursor, int* __restrict__ csr){
  int e = blockIdx.x*256 + threadIdx.x; int ET = E + N;
  if (e >= ET) return;
  int src, dst;
  if (e < E){ src = ei[e]; dst = ei[E + e]; } else { src = e - E; dst = src; }
  int pos = offs[dst] + atomicAdd(&cursor[dst], 1);
  csr[pos] = src;
}

// ---------------- f32 GEMM -> bf16 output: Yb[M x 128] = A[M x 128] @ W[128 x 128] (row scale rsqrt(deg)) ----------------
#define TM 64
__global__ __launch_bounds__(256) void k_gemm128(const float* __restrict__ A, const float* __restrict__ W,
                                                 unsigned* __restrict__ Yb, int M, const int* __restrict__ deg){
  __shared__ float As[TM][128];
  __shared__ float Ws[128][128];
  int tid = threadIdx.x;
  int row0 = blockIdx.x * TM;
  {
    const float4* Wv = (const float4*)W;
    float4* Wsv = (float4*)&Ws[0][0];
    for (int i = tid; i < 128*32; i += 256) Wsv[i] = Wv[i];
  }
  for (int i = tid; i < TM*32; i += 256){
    int r = i >> 5, c4 = i & 31; int gr = row0 + r;
    float4 v = (gr < M) ? ((const float4*)A)[(size_t)gr*32 + c4] : make_float4(0.f,0.f,0.f,0.f);
    ((float4*)&As[r][0])[c4] = v;
  }
  __syncthreads();
  int ty = tid >> 4, tx = tid & 15;
  int r0 = ty * 4, c0 = tx * 8;
  float acc[4][8] = {};
  #pragma unroll 4
  for (int k = 0; k < 128; ++k){
    float a0 = As[r0][k], a1 = As[r0+1][k], a2 = As[r0+2][k], a3 = As[r0+3][k];
    float4 w0 = *(const float4*)&Ws[k][c0];
    float4 w1 = *(const float4*)&Ws[k][c0+4];
    float wv[8] = {w0.x,w0.y,w0.z,w0.w,w1.x,w1.y,w1.z,w1.w};
    #pragma unroll
    for (int j = 0; j < 8; ++j){
      acc[0][j] += a0*wv[j];
      acc[1][j] += a1*wv[j];
      acc[2][j] += a2*wv[j];
      acc[3][j] += a3*wv[j];
    }
  }
  #pragma unroll
  for (int i2 = 0; i2 < 4; ++i2){
    int gr = row0 + r0 + i2;
    if (gr >= M) continue;
    float sc = deg ? rsqrtf((float)deg[gr]) : 1.0f;
    uint4 o;
    o.x = bfpack2(acc[i2][0]*sc, acc[i2][1]*sc);
    o.y = bfpack2(acc[i2][2]*sc, acc[i2][3]*sc);
    o.z = bfpack2(acc[i2][4]*sc, acc[i2][5]*sc);
    o.w = bfpack2(acc[i2][6]*sc, acc[i2][7]*sc);
    ((uint4*)&Yb[(size_t)gr*64])[tx] = o;
  }
}

// ---------------- GAT: per-node attention logits (a_src, a_dst), from bf16 Y ----------------
__global__ __launch_bounds__(256) void k_attn(const unsigned* __restrict__ Yb, const float* __restrict__ asrcw,
                                              const float* __restrict__ adstw,
                                              float* __restrict__ a_src, float* __restrict__ a_dst, int N){
  int n = (blockIdx.x*256 + threadIdx.x) >> 6;
  int lane = threadIdx.x & 63;
  if (n >= N) return;
  int head = lane >> 4;
  int d0 = (lane & 15) * 2;
  unsigned u = Yb[(size_t)n*64 + lane];
  float h0 = bflo(u), h1 = bfhi(u);
  float vs = h0 * asrcw[head*32 + d0] + h1 * asrcw[head*32 + d0 + 1];
  float vd = h0 * adstw[head*32 + d0] + h1 * adstw[head*32 + d0 + 1];
  #pragma unroll
  for (int m = 1; m < 16; m <<= 1){
    vs += __shfl_xor(vs, m, 64);
    vd += __shfl_xor(vd, m, 64);
  }
  if ((lane & 15) == 0){
    a_src[n*4 + head] = vs;
    a_dst[n*4 + head] = vd;
  }
}

// ---------------- GAT aggregation: two-phase softmax, wave per node ----------------
__global__ __launch_bounds__(256) void k_gat_agg(const unsigned* __restrict__ Yb, const int* __restrict__ csr,
                                                 const int* __restrict__ offs, const int* __restrict__ deg,
                                                 const float* __restrict__ a_src, const float4* __restrict__ adst4,
                                                 const float* __restrict__ bias, float* __restrict__ out, int N){
  int n = (blockIdx.x*256 + threadIdx.x) >> 6;
  int lane = threadIdx.x & 63;
  if (n >= N) return;
  int beg = offs[n], d = deg[n];
  float4 adn = adst4[n];
  const float4* asrc4 = (const float4*)a_src;

  // ---- phase 1: per-head (max, sum) -- lanes stride edges cooperatively ----
  float m0=-1e30f, m1=-1e30f, m2=-1e30f, m3=-1e30f;
  float s0=0.f, s1=0.f, s2=0.f, s3=0.f;
  for (int i = lane; i < d; i += 64){
    int sn = csr[beg + i];
    float4 as = asrc4[sn];
    float e0 = as.x + adn.x; e0 = e0 > 0.f ? e0 : 0.2f*e0;
    float e1 = as.y + adn.y; e1 = e1 > 0.f ? e1 : 0.2f*e1;
    float e2 = as.z + adn.z; e2 = e2 > 0.f ? e2 : 0.2f*e2;
    float e3 = as.w + adn.w; e3 = e3 > 0.f ? e3 : 0.2f*e3;
    float mn;
    mn = fmaxf(m0, e0); s0 = s0*__expf(m0-mn) + __expf(e0-mn); m0 = mn;
    mn = fmaxf(m1, e1); s1 = s1*__expf(m1-mn) + __expf(e1-mn); m1 = mn;
    mn = fmaxf(m2, e2); s2 = s2*__expf(m2-mn) + __expf(e2-mn); m2 = mn;
    mn = fmaxf(m3, e3); s3 = s3*__expf(m3-mn) + __expf(e3-mn); m3 = mn;
  }
  #pragma unroll
  for (int w = 1; w < 64; w <<= 1){
    float mm, ss, mn;
    mm = __shfl_xor(m0, w, 64); ss = __shfl_xor(s0, w, 64);
    mn = fmaxf(m0, mm); s0 = s0*__expf(m0-mn) + ss*__expf(mm-mn); m0 = mn;
    mm = __shfl_xor(m1, w, 64); ss = __shfl_xor(s1, w, 64);
    mn = fmaxf(m1, mm); s1 = s1*__expf(m1-mn) + ss*__expf(mm-mn); m1 = mn;
    mm = __shfl_xor(m2, w, 64); ss = __shfl_xor(s2, w, 64);
    mn = fmaxf(m2, mm); s2 = s2*__expf(m2-mn) + ss*__expf(mm-mn); m2 = mn;
    mm = __shfl_xor(m3, w, 64); ss = __shfl_xor(s3, w, 64);
    mn = fmaxf(m3, mm); s3 = s3*__expf(m3-mn) + ss*__expf(mm-mn); m3 = mn;
  }
  int head = lane >> 4;
  float mh  = head < 2 ? (head == 0 ? m0 : m1) : (head == 2 ? m2 : m3);
  float sh  = head < 2 ? (head == 0 ? s0 : s1) : (head == 2 ? s2 : s3);
  float adh = head < 2 ? (head == 0 ? adn.x : adn.y) : (head == 2 ? adn.z : adn.w);
  float inv = 1.f / sh;

  // ---- phase 2: weighted gather ----
  float accx = 0.f, accy = 0.f;
  int i = 0;
  for (; i + 4 <= d; i += 4){
    int n0 = csr[beg+i], n1 = csr[beg+i+1], n2 = csr[beg+i+2], n3 = csr[beg+i+3];
    float e0 = a_src[n0*4+head], e1 = a_src[n1*4+head], e2 = a_src[n2*4+head], e3 = a_src[n3*4+head];
    unsigned v0 = Yb[(size_t)n0*64+lane], v1 = Yb[(size_t)n1*64+lane],
             v2 = Yb[(size_t)n2*64+lane], v3 = Yb[(size_t)n3*64+lane];
    float ee[4] = {e0, e1, e2, e3};
    unsigned vv[4] = {v0, v1, v2, v3};
    #pragma unroll
    for (int j = 0; j < 4; ++j){
      float e = ee[j] + adh; e = e > 0.f ? e : 0.2f*e;
      float p = __expf(e - mh);
      accx += p * bflo(vv[j]);
      accy += p * bfhi(vv[j]);
    }
  }
  for (; i < d; ++i){
    int sn = csr[beg+i];
    float e = a_src[sn*4+head] + adh; e = e > 0.f ? e : 0.2f*e;
    float p = __expf(e - mh);
    unsigned v = Yb[(size_t)sn*64 + lane];
    accx += p * bflo(v);
    accy += p * bfhi(v);
  }
  float2 b = ((const float2*)bias)[lane];
  float z0 = accx*inv + b.x, z1 = accy*inv + b.y;
  z0 = z0 > 0.f ? z0 : expm1f(z0);
  z1 = z1 > 0.f ? z1 : expm1f(z1);
  ((float2*)out)[(size_t)n*64 + lane] = make_float2(z0, z1);
}

// ---------------- GCN aggregation + folded BN + ELU + residual, wave per node, bf16 gather ----------------
__global__ __launch_bounds__(256) void k_gcn_agg(const unsigned* __restrict__ Yb, const float* __restrict__ resid,
                                                 float* __restrict__ out, const int* __restrict__ csr,
                                                 const int* __restrict__ offs, const int* __restrict__ deg,
                                                 const float* __restrict__ gb, const float* __restrict__ bg,
                                                 const float* __restrict__ bb, const float* __restrict__ bm,
                                                 const float* __restrict__ bv, int N){
  int n = (blockIdx.x*256 + threadIdx.x) >> 6;
  int lane = threadIdx.x & 63;
  if (n >= N) return;
  int beg = offs[n], d = deg[n];
  float ax = 0.f, ay = 0.f;
  int i = 0;
  for (; i + 4 <= d; i += 4){
    int s0 = csr[beg+i], s1 = csr[beg+i+1], s2 = csr[beg+i+2], s3 = csr[beg+i+3];
    unsigned v0 = Yb[(size_t)s0*64+lane], v1 = Yb[(size_t)s1*64+lane],
             v2 = Yb[(size_t)s2*64+lane], v3 = Yb[(size_t)s3*64+lane];
    ax += bflo(v0) + bflo(v1) + bflo(v2) + bflo(v3);
    ay += bfhi(v0) + bfhi(v1) + bfhi(v2) + bfhi(v3);
  }
  for (; i < d; ++i){
    int sc = csr[beg+i];
    unsigned v = Yb[(size_t)sc*64 + lane];
    ax += bflo(v); ay += bfhi(v);
  }
  float dinv = rsqrtf((float)d);
  float2 g  = ((const float2*)bg)[lane];
  float2 b  = ((const float2*)bb)[lane];
  float2 mm = ((const float2*)bm)[lane];
  float2 vv = ((const float2*)bv)[lane];
  float2 gb2 = ((const float2*)gb)[lane];
  float A0 = g.x * rsqrtf(vv.x + BN_EPS), A1 = g.y * rsqrtf(vv.y + BN_EPS);
  float z0 = ax*dinv*A0 + (gb2.x - mm.x)*A0 + b.x;
  float z1 = ay*dinv*A1 + (gb2.y - mm.y)*A1 + b.y;
  z0 = z0 > 0.f ? z0 : expm1f(z0);
  z1 = z1 > 0.f ? z1 : expm1f(z1);
  if (resid){
    float2 r = ((const float2*)resid)[(size_t)n*64 + lane];
    z0 += r.x; z1 += r.y;
  }
  ((float2*)out)[(size_t)n*64 + lane] = make_float2(z0, z1);
}

// ---------------- mean pool per graph (batch sorted) ----------------
__global__ __launch_bounds__(128) void k_pool(const float* __restrict__ H, const int* __restrict__ batch,
                                              float* __restrict__ G, int N){
  int gid = blockIdx.x; int c = threadIdx.x;
  int lo = 0, hi = N;
  while (lo < hi){ int mid = (lo + hi) >> 1; if (batch[mid] < gid) lo = mid + 1; else hi = mid; }
  int start = lo;
  lo = start; hi = N;
  while (lo < hi){ int mid = (lo + hi) >> 1; if (batch[mid] < gid + 1) lo = mid + 1; else hi = mid; }
  int end = lo;
  float acc = 0.f;
  for (int r = start; r < end; ++r) acc += H[(size_t)r*128 + c];
  float cnt = (float)(end - start);
  G[gid*128 + c] = acc / fmaxf(cnt, 1.0f);
}

// ---------------- MLP head ----------------
__global__ __launch_bounds__(128) void k_mlp(const float* __restrict__ G, const float* __restrict__ p1w,
                                             const float* __restrict__ p1b, const float* __restrict__ p2w,
                                             const float* __restrict__ p2b, const float* __restrict__ cw,
                                             const float* __restrict__ cb, float* __restrict__ out, int NG){
  int gid = blockIdx.x; int t = threadIdx.x;
  __shared__ float gv[128], t1[128], e[64];
  gv[t] = G[gid*128 + t];
  __syncthreads();
  float acc = p1b[t];
  for (int k = 0; k < 128; ++k) acc += gv[k] * p1w[k*128 + t];
  t1[t] = acc > 0.f ? acc : expm1f(acc);
  __syncthreads();
  if (t < 64){
    float a = p2b[t];
    for (int k = 0; k < 128; ++k) a += t1[k] * p2w[k*64 + t];
    e[t] = a;
    out[NG*3 + gid*64 + t] = a;   // emb output
  }
  __syncthreads();
  if (t < 3){
    float a = cb[t];
    for (int k = 0; k < 64; ++k) a += e[k] * cw[k*3 + t];
    out[gid*3 + t] = a;           // logits output
  }
}

extern "C" void kernel_launch(void* const* d_in, const int* in_sizes, int n_in,
                              void* d_out, int out_size, void* d_ws, size_t ws_size,
                              hipStream_t stream){
  const float* x      = (const float*)d_in[0];
  const int*   ei     = (const int*)d_in[1];
  const int*   batch  = (const int*)d_in[3];
  const float* gat_w  = (const float*)d_in[4];
  const float* att_s  = (const float*)d_in[5];
  const float* att_d  = (const float*)d_in[6];
  const float* gat_b  = (const float*)d_in[7];
  const float* w1 = (const float*)d_in[8];  const float* b1 = (const float*)d_in[9];
  const float* bn1g = (const float*)d_in[10], *bn1b = (const float*)d_in[11],
             * bn1m = (const float*)d_in[12], *bn1v = (const float*)d_in[13];
  const float* w2 = (const float*)d_in[14]; const float* b2 = (const float*)d_in[15];
  const float* bn2g = (const float*)d_in[16], *bn2b = (const float*)d_in[17],
             * bn2m = (const float*)d_in[18], *bn2v = (const float*)d_in[19];
  const float* w3 = (const float*)d_in[20]; const float* b3 = (const float*)d_in[21];
  const float* bn3g = (const float*)d_in[22], *bn3b = (const float*)d_in[23],
             * bn3m = (const float*)d_in[24], *bn3v = (const float*)d_in[25];
  const float* p1w = (const float*)d_in[26]; const float* p1b = (const float*)d_in[27];
  const float* p2w = (const float*)d_in[28]; const float* p2b = (const float*)d_in[29];
  const float* cw  = (const float*)d_in[30]; const float* cb  = (const float*)d_in[31];

  int N  = in_sizes[3];
  int E  = in_sizes[1] / 2;
  int ET = E + N;
  int NG = out_size / 67;   // 1024 graphs (3 + 64 outputs each)

  char* ws = (char*)d_ws;
  size_t off = 0;
  auto alloc = [&](size_t bytes) -> void* {
    void* p = ws + off;
    off = (off + bytes + 255) & ~(size_t)255;
    return p;
  };
  float*    A    = (float*)alloc((size_t)N * 128 * 4);
  float*    B    = (float*)alloc((size_t)N * 128 * 4);
  unsigned* Yb   = (unsigned*)alloc((size_t)N * 64 * 4);   // bf16 x2 packed
  int*      csr  = (int*)alloc((size_t)ET * 4);
  int*      deg  = (int*)alloc((size_t)N * 4);
  int*      offs = (int*)alloc((size_t)N * 4);
  int*      curs = (int*)alloc((size_t)N * 4);
  int*      part = (int*)alloc(1024 * 4);
  float*    asrc = (float*)alloc((size_t)N * 4 * 4);
  float*    adst = (float*)alloc((size_t)N * 4 * 4);
  float*    G    = (float*)alloc((size_t)NG * 128 * 4);

  hipMemsetAsync(deg,  0, (size_t)N * 4, stream);
  hipMemsetAsync(curs, 0, (size_t)N * 4, stream);

  int nb = (N + 1023) / 1024;
  k_count<<<(ET + 255)/256, 256, 0, stream>>>(ei, E, N, deg);
  k_scan_block<<<nb, 1024, 0, stream>>>(deg, offs, part, N);
  k_scan_part<<<1, 1, 0, stream>>>(part, nb);
  k_add_part<<<(N + 255)/256, 256, 0, stream>>>(offs, part, N);
  k_fill<<<(ET + 255)/256, 256, 0, stream>>>(ei, E, N, offs, curs, csr);

  int gblk = (N + TM - 1) / TM;
  int ablk = (N + 3) / 4;

  // GAT
  k_gemm128<<<gblk, 256, 0, stream>>>(x, gat_w, Yb, N, nullptr);
  k_attn<<<ablk, 256, 0, stream>>>(Yb, att_s, att_d, asrc, adst, N);
  k_gat_agg<<<ablk, 256, 0, stream>>>(Yb, csr, offs, deg, asrc, (const float4*)adst, gat_b, A, N);

  // GCN 1 (residual A), out B
  k_gemm128<<<gblk, 256, 0, stream>>>(A, w1, Yb, N, deg);
  k_gcn_agg<<<ablk, 256, 0, stream>>>(Yb, A, B, csr, offs, deg, b1, bn1g, bn1b, bn1m, bn1v, N);
  // GCN 2 (residual B), out A
  k_gemm128<<<gblk, 256, 0, stream>>>(B, w2, Yb, N, deg);
  k_gcn_agg<<<ablk, 256, 0, stream>>>(Yb, B, A, csr, offs, deg, b2, bn2g, bn2b, bn2m, bn2v, N);
  // GCN 3 (no residual), out B
  k_gemm128<<<gblk, 256, 0, stream>>>(A, w3, Yb, N, deg);
  k_gcn_agg<<<ablk, 256, 0, stream>>>(Yb, nullptr, B, csr, offs, deg, b3, bn3g, bn3b, bn3m, bn3v, N);

  // pool + head
  k_pool<<<NG, 128, 0, stream>>>(B, batch, G, N);
  k_mlp<<<NG, 128, 0, stream>>>(G, p1w, p1b, p2w, p2b, cw, cb, (float*)d_out, NG);
}

// Round 3
// 770.261 us; speedup vs baseline: 1.4715x; 1.3421x over previous
//
#include <hip/hip_runtime.h>
#include <math.h>

#define BN_EPS 1e-5f
typedef unsigned short u16;
typedef __attribute__((ext_vector_type(8))) short bf16x8;
typedef __attribute__((ext_vector_type(4))) float f32x4;

// ---------- bf16 helpers ----------
__device__ inline unsigned bfpack2(float a, float b){
  unsigned ua = __float_as_uint(a); ua = (ua + 0x7fffu + ((ua >> 16) & 1u)) >> 16;
  unsigned ub = __float_as_uint(b); ub = (ub + 0x7fffu + ((ub >> 16) & 1u)) >> 16;
  return ua | (ub << 16);
}
__device__ inline u16 bf16of(float a){
  unsigned ua = __float_as_uint(a); return (u16)((ua + 0x7fffu + ((ua >> 16) & 1u)) >> 16);
}
__device__ inline float bflo(unsigned u){ return __uint_as_float(u << 16); }
__device__ inline float bfhi(unsigned u){ return __uint_as_float(u & 0xffff0000u); }

// ---------------- preprocessing: CSR by dst ----------------
__global__ void k_count(const int* __restrict__ ei, int E, int N, int* __restrict__ deg){
  int e = blockIdx.x*256 + threadIdx.x;
  int ET = E + N;
  if (e >= ET) return;
  int dst = (e < E) ? ei[E + e] : (e - E);
  atomicAdd(&deg[dst], 1);
}

__global__ __launch_bounds__(1024) void k_scan_block(const int* __restrict__ deg, int* __restrict__ offs,
                                                     int* __restrict__ part, int N){
  __shared__ int sh[1024];
  int t = threadIdx.x; int i = blockIdx.x*1024 + t;
  int v = (i < N) ? deg[i] : 0;
  sh[t] = v; __syncthreads();
  for (int off = 1; off < 1024; off <<= 1){
    int u = (t >= off) ? sh[t - off] : 0;
    __syncthreads();
    sh[t] += u;
    __syncthreads();
  }
  if (i < N) offs[i] = sh[t] - v;
  if (t == 1023) part[blockIdx.x] = sh[1023];
}

__global__ void k_scan_part(int* part, int nb){
  if (threadIdx.x == 0 && blockIdx.x == 0){
    int s = 0;
    for (int i = 0; i < nb; ++i){ int v = part[i]; part[i] = s; s += v; }
  }
}

__global__ void k_add_part(int* __restrict__ offs, const int* __restrict__ part, int N){
  int i = blockIdx.x*256 + threadIdx.x;
  if (i < N) offs[i] += part[i >> 10];
}

__global__ void k_fill(const int* __restrict__ ei, int E, int N, const int* __restrict__ offs,
                       int* __restrict__ cursor, int* __restrict__ csr, int* __restrict__ csrd){
  int e = blockIdx.x*256 + threadIdx.x; int ET = E + N;
  if (e >= ET) return;
  int src, dst;
  if (e < E){ src = ei[e]; dst = ei[E + e]; } else { src = e - E; dst = src; }
  int pos = offs[dst] + atomicAdd(&cursor[dst], 1);
  csr[pos] = src;
  csrd[pos] = dst;
}

// ---------------- weight convert: WbT[n][k] = bf16(W[k][n]) ----------------
__global__ void k_wconv(const float* __restrict__ W, u16* __restrict__ WbT){
  int id = blockIdx.x*256 + threadIdx.x;   // 16384
  int nn = id >> 7, kk = id & 127;
  WbT[id] = bf16of(W[kk*128 + nn]);
}

// ---------------- MFMA GEMM: Yb[M x 128](bf16) = bf16(A[M x 128]) @ WbT^T, row scale rsqrt(deg) ----------------
__global__ __launch_bounds__(256, 2) void k_gemm_mfma(const float* __restrict__ A,
                                                      const u16* __restrict__ WbT,
                                                      u16* __restrict__ Yb, int M,
                                                      const int* __restrict__ deg){
  int lane = threadIdx.x & 63;
  int wv   = threadIdx.x >> 6;
  int row0 = blockIdx.x * 64 + wv * 16;       // 16 rows per wave
  int rA   = row0 + (lane & 15);              // A-fragment row for this lane
  if (rA >= M) rA = M - 1;                    // clamp; stores guarded below
  int g    = lane >> 4;                       // k-group 0..3

  // A fragments: lane holds A[rA][s*32 + g*8 + j], j=0..7, converted to bf16
  bf16x8 afr[4];
  const float* ap = A + (size_t)rA*128 + g*8;
  #pragma unroll
  for (int s = 0; s < 4; ++s){
    float4 f0 = *(const float4*)(ap + s*32);
    float4 f1 = *(const float4*)(ap + s*32 + 4);
    union { bf16x8 v; unsigned u[4]; } tmp;
    tmp.u[0] = bfpack2(f0.x, f0.y);
    tmp.u[1] = bfpack2(f0.z, f0.w);
    tmp.u[2] = bfpack2(f1.x, f1.y);
    tmp.u[3] = bfpack2(f1.z, f1.w);
    afr[s] = tmp.v;
  }

  f32x4 acc[8] = {};
  // K loop: per k-step load B fragments for all 8 n-tiles, then 8 MFMAs
  #pragma unroll
  for (int s = 0; s < 4; ++s){
    union BU { uint4 q; bf16x8 v; } b[8];
    #pragma unroll
    for (int t = 0; t < 8; ++t){
      int col = t*16 + (lane & 15);
      b[t].q = ((const uint4*)(WbT + (size_t)col*128))[s*4 + g];
    }
    #pragma unroll
    for (int t = 0; t < 8; ++t)
      acc[t] = __builtin_amdgcn_mfma_f32_16x16x32_bf16(afr[s], b[t].v, acc[t], 0, 0, 0);
  }

  // C/D layout: col = lane&15 (+t*16), row = (lane>>4)*4 + j (+row0)
  int orow = row0 + (lane >> 4)*4;
  #pragma unroll
  for (int j = 0; j < 4; ++j){
    int r = orow + j;
    if (r < M){
      float sc = deg ? rsqrtf((float)deg[r]) : 1.0f;
      #pragma unroll
      for (int t = 0; t < 8; ++t)
        Yb[(size_t)r*128 + t*16 + (lane & 15)] = bf16of(acc[t][j] * sc);
    }
  }
}

// ---------------- GAT: per-node attention logits (a_src, a_dst), from bf16 Y ----------------
__global__ __launch_bounds__(256) void k_attn(const unsigned* __restrict__ Yb, const float* __restrict__ asrcw,
                                              const float* __restrict__ adstw,
                                              float* __restrict__ a_src, float* __restrict__ a_dst, int N){
  int n = (blockIdx.x*256 + threadIdx.x) >> 6;
  int lane = threadIdx.x & 63;
  if (n >= N) return;
  int head = lane >> 4;
  int d0 = (lane & 15) * 2;
  unsigned u = Yb[(size_t)n*64 + lane];
  float h0 = bflo(u), h1 = bfhi(u);
  float vs = h0 * asrcw[head*32 + d0] + h1 * asrcw[head*32 + d0 + 1];
  float vd = h0 * adstw[head*32 + d0] + h1 * adstw[head*32 + d0 + 1];
  #pragma unroll
  for (int m = 1; m < 16; m <<= 1){
    vs += __shfl_xor(vs, m, 64);
    vd += __shfl_xor(vd, m, 64);
  }
  if ((lane & 15) == 0){
    a_src[n*4 + head] = vs;
    a_dst[n*4 + head] = vd;
  }
}

// ---------------- edge weights: w = exp(leaky(a_src[src] + a_dst[dst])) (no max-sub; logits bounded) ----------------
__global__ void k_edge_w(const int* __restrict__ csr, const int* __restrict__ csrd,
                         const float4* __restrict__ asrc4, const float4* __restrict__ adst4,
                         float4* __restrict__ wE, int ET){
  int i = blockIdx.x*256 + threadIdx.x;
  if (i >= ET) return;
  int s = csr[i], dd = csrd[i];
  float4 as = asrc4[s], ad = adst4[dd];
  float e0 = as.x + ad.x; e0 = e0 > 0.f ? e0 : 0.2f*e0;
  float e1 = as.y + ad.y; e1 = e1 > 0.f ? e1 : 0.2f*e1;
  float e2 = as.z + ad.z; e2 = e2 > 0.f ? e2 : 0.2f*e2;
  float e3 = as.w + ad.w; e3 = e3 > 0.f ? e3 : 0.2f*e3;
  wE[i] = make_float4(__expf(e0), __expf(e1), __expf(e2), __expf(e3));
}

// ---------------- GAT aggregation: pure weighted gather, wave per node ----------------
__global__ __launch_bounds__(256) void k_gat_agg(const unsigned* __restrict__ Yb, const int* __restrict__ csr,
                                                 const int* __restrict__ offs, const int* __restrict__ deg,
                                                 const float* __restrict__ wE, const float* __restrict__ bias,
                                                 float* __restrict__ out, int N){
  int n = (blockIdx.x*256 + threadIdx.x) >> 6;
  int lane = threadIdx.x & 63;
  if (n >= N) return;
  int head = lane >> 4;
  int beg = offs[n], d = deg[n];
  const int* cp = csr + beg;
  const float* wp = wE + (size_t)beg*4 + head;
  float accx = 0.f, accy = 0.f, sw = 0.f;
  int i = 0;
  for (; i + 4 <= d; i += 4){
    int n0 = cp[i], n1 = cp[i+1], n2 = cp[i+2], n3 = cp[i+3];
    float w0 = wp[i*4], w1 = wp[i*4+4], w2 = wp[i*4+8], w3 = wp[i*4+12];
    unsigned v0 = Yb[(size_t)n0*64+lane], v1 = Yb[(size_t)n1*64+lane],
             v2 = Yb[(size_t)n2*64+lane], v3 = Yb[(size_t)n3*64+lane];
    accx += w0*bflo(v0) + w1*bflo(v1) + w2*bflo(v2) + w3*bflo(v3);
    accy += w0*bfhi(v0) + w1*bfhi(v1) + w2*bfhi(v2) + w3*bfhi(v3);
    sw   += (w0 + w1) + (w2 + w3);
  }
  for (; i < d; ++i){
    int sn = cp[i];
    float w = wp[i*4];
    unsigned v = Yb[(size_t)sn*64 + lane];
    accx += w * bflo(v);
    accy += w * bfhi(v);
    sw   += w;
  }
  float inv = 1.f / sw;
  float2 b = ((const float2*)bias)[lane];
  float z0 = accx*inv + b.x, z1 = accy*inv + b.y;
  z0 = z0 > 0.f ? z0 : expm1f(z0);
  z1 = z1 > 0.f ? z1 : expm1f(z1);
  ((float2*)out)[(size_t)n*64 + lane] = make_float2(z0, z1);
}

// ---------------- GCN aggregation + folded BN + ELU + residual, wave per node, bf16 gather ----------------
__global__ __launch_bounds__(256) void k_gcn_agg(const unsigned* __restrict__ Yb, const float* __restrict__ resid,
                                                 float* __restrict__ out, const int* __restrict__ csr,
                                                 const int* __restrict__ offs, const int* __restrict__ deg,
                                                 const float* __restrict__ gb, const float* __restrict__ bg,
                                                 const float* __restrict__ bb, const float* __restrict__ bm,
                                                 const float* __restrict__ bv, int N){
  int n = (blockIdx.x*256 + threadIdx.x) >> 6;
  int lane = threadIdx.x & 63;
  if (n >= N) return;
  int beg = offs[n], d = deg[n];
  const int* cp = csr + beg;
  float ax = 0.f, ay = 0.f;
  int i = 0;
  for (; i + 4 <= d; i += 4){
    int s0 = cp[i], s1 = cp[i+1], s2 = cp[i+2], s3 = cp[i+3];
    unsigned v0 = Yb[(size_t)s0*64+lane], v1 = Yb[(size_t)s1*64+lane],
             v2 = Yb[(size_t)s2*64+lane], v3 = Yb[(size_t)s3*64+lane];
    ax += (bflo(v0) + bflo(v1)) + (bflo(v2) + bflo(v3));
    ay += (bfhi(v0) + bfhi(v1)) + (bfhi(v2) + bfhi(v3));
  }
  for (; i < d; ++i){
    int sc = cp[i];
    unsigned v = Yb[(size_t)sc*64 + lane];
    ax += bflo(v); ay += bfhi(v);
  }
  float dinv = rsqrtf((float)d);
  float2 g  = ((const float2*)bg)[lane];
  float2 b  = ((const float2*)bb)[lane];
  float2 mm = ((const float2*)bm)[lane];
  float2 vv = ((const float2*)bv)[lane];
  float2 gb2 = ((const float2*)gb)[lane];
  float A0 = g.x * rsqrtf(vv.x + BN_EPS), A1 = g.y * rsqrtf(vv.y + BN_EPS);
  float z0 = ax*dinv*A0 + (gb2.x - mm.x)*A0 + b.x;
  float z1 = ay*dinv*A1 + (gb2.y - mm.y)*A1 + b.y;
  z0 = z0 > 0.f ? z0 : expm1f(z0);
  z1 = z1 > 0.f ? z1 : expm1f(z1);
  if (resid){
    float2 r = ((const float2*)resid)[(size_t)n*64 + lane];
    z0 += r.x; z1 += r.y;
  }
  ((float2*)out)[(size_t)n*64 + lane] = make_float2(z0, z1);
}

// ---------------- mean pool per graph (batch sorted) ----------------
__global__ __launch_bounds__(128) void k_pool(const float* __restrict__ H, const int* __restrict__ batch,
                                              float* __restrict__ G, int N){
  int gid = blockIdx.x; int c = threadIdx.x;
  int lo = 0, hi = N;
  while (lo < hi){ int mid = (lo + hi) >> 1; if (batch[mid] < gid) lo = mid + 1; else hi = mid; }
  int start = lo;
  lo = start; hi = N;
  while (lo < hi){ int mid = (lo + hi) >> 1; if (batch[mid] < gid + 1) lo = mid + 1; else hi = mid; }
  int end = lo;
  float acc = 0.f;
  for (int r = start; r < end; ++r) acc += H[(size_t)r*128 + c];
  float cnt = (float)(end - start);
  G[gid*128 + c] = acc / fmaxf(cnt, 1.0f);
}

// ---------------- MLP head ----------------
__global__ __launch_bounds__(128) void k_mlp(const float* __restrict__ G, const float* __restrict__ p1w,
                                             const float* __restrict__ p1b, const float* __restrict__ p2w,
                                             const float* __restrict__ p2b, const float* __restrict__ cw,
                                             const float* __restrict__ cb, float* __restrict__ out, int NG){
  int gid = blockIdx.x; int t = threadIdx.x;
  __shared__ float gv[128], t1[128], e[64];
  gv[t] = G[gid*128 + t];
  __syncthreads();
  float acc = p1b[t];
  for (int k = 0; k < 128; ++k) acc += gv[k] * p1w[k*128 + t];
  t1[t] = acc > 0.f ? acc : expm1f(acc);
  __syncthreads();
  if (t < 64){
    float a = p2b[t];
    for (int k = 0; k < 128; ++k) a += t1[k] * p2w[k*64 + t];
    e[t] = a;
    out[NG*3 + gid*64 + t] = a;
  }
  __syncthreads();
  if (t < 3){
    float a = cb[t];
    for (int k = 0; k < 64; ++k) a += e[k] * cw[k*3 + t];
    out[gid*3 + t] = a;
  }
}

extern "C" void kernel_launch(void* const* d_in, const int* in_sizes, int n_in,
                              void* d_out, int out_size, void* d_ws, size_t ws_size,
                              hipStream_t stream){
  const float* x      = (const float*)d_in[0];
  const int*   ei     = (const int*)d_in[1];
  const int*   batch  = (const int*)d_in[3];
  const float* gat_w  = (const float*)d_in[4];
  const float* att_s  = (const float*)d_in[5];
  const float* att_d  = (const float*)d_in[6];
  const float* gat_b  = (const float*)d_in[7];
  const float* w1 = (const float*)d_in[8];  const float* b1 = (const float*)d_in[9];
  const float* bn1g = (const float*)d_in[10], *bn1b = (const float*)d_in[11],
             * bn1m = (const float*)d_in[12], *bn1v = (const float*)d_in[13];
  const float* w2 = (const float*)d_in[14]; const float* b2 = (const float*)d_in[15];
  const float* bn2g = (const float*)d_in[16], *bn2b = (const float*)d_in[17],
             * bn2m = (const float*)d_in[18], *bn2v = (const float*)d_in[19];
  const float* w3 = (const float*)d_in[20]; const float* b3 = (const float*)d_in[21];
  const float* bn3g = (const float*)d_in[22], *bn3b = (const float*)d_in[23],
             * bn3m = (const float*)d_in[24], *bn3v = (const float*)d_in[25];
  const float* p1w = (const float*)d_in[26]; const float* p1b = (const float*)d_in[27];
  const float* p2w = (const float*)d_in[28]; const float* p2b = (const float*)d_in[29];
  const float* cw  = (const float*)d_in[30]; const float* cb  = (const float*)d_in[31];

  int N  = in_sizes[3];
  int E  = in_sizes[1] / 2;
  int ET = E + N;
  int NG = out_size / 67;

  char* ws = (char*)d_ws;
  size_t off = 0;
  auto alloc = [&](size_t bytes) -> void* {
    void* p = ws + off;
    off = (off + bytes + 255) & ~(size_t)255;
    return p;
  };
  float*    A    = (float*)alloc((size_t)N * 128 * 4);
  float*    Bact = (float*)alloc((size_t)N * 128 * 4);
  u16*      Yb   = (u16*)alloc((size_t)N * 128 * 2);
  int*      csr  = (int*)alloc((size_t)ET * 4);
  int*      csrd = (int*)alloc((size_t)ET * 4);
  int*      deg  = (int*)alloc((size_t)N * 4);
  int*      offs = (int*)alloc((size_t)N * 4);
  int*      curs = (int*)alloc((size_t)N * 4);
  int*      part = (int*)alloc(1024 * 4);
  float*    asrc = (float*)alloc((size_t)N * 4 * 4);
  float*    adst = (float*)alloc((size_t)N * 4 * 4);
  float*    wE   = (float*)alloc((size_t)ET * 4 * 4);
  float*    G    = (float*)alloc((size_t)NG * 128 * 4);
  u16*      WbG  = (u16*)alloc(16384 * 2);
  u16*      Wb1  = (u16*)alloc(16384 * 2);
  u16*      Wb2  = (u16*)alloc(16384 * 2);
  u16*      Wb3  = (u16*)alloc(16384 * 2);

  hipMemsetAsync(deg,  0, (size_t)N * 4, stream);
  hipMemsetAsync(curs, 0, (size_t)N * 4, stream);

  int nb = (N + 1023) / 1024;
  k_count<<<(ET + 255)/256, 256, 0, stream>>>(ei, E, N, deg);
  k_scan_block<<<nb, 1024, 0, stream>>>(deg, offs, part, N);
  k_scan_part<<<1, 1, 0, stream>>>(part, nb);
  k_add_part<<<(N + 255)/256, 256, 0, stream>>>(offs, part, N);
  k_fill<<<(ET + 255)/256, 256, 0, stream>>>(ei, E, N, offs, curs, csr, csrd);

  k_wconv<<<64, 256, 0, stream>>>(gat_w, WbG);
  k_wconv<<<64, 256, 0, stream>>>(w1, Wb1);
  k_wconv<<<64, 256, 0, stream>>>(w2, Wb2);
  k_wconv<<<64, 256, 0, stream>>>(w3, Wb3);

  int gblk = (N + 63) / 64;
  int ablk = (N + 3) / 4;

  // GAT
  k_gemm_mfma<<<gblk, 256, 0, stream>>>(x, WbG, Yb, N, nullptr);
  k_attn<<<ablk, 256, 0, stream>>>((const unsigned*)Yb, att_s, att_d, asrc, adst, N);
  k_edge_w<<<(ET + 255)/256, 256, 0, stream>>>(csr, csrd, (const float4*)asrc, (const float4*)adst,
                                               (float4*)wE, ET);
  k_gat_agg<<<ablk, 256, 0, stream>>>((const unsigned*)Yb, csr, offs, deg, wE, gat_b, A, N);

  // GCN 1 (residual A), out Bact
  k_gemm_mfma<<<gblk, 256, 0, stream>>>(A, Wb1, Yb, N, deg);
  k_gcn_agg<<<ablk, 256, 0, stream>>>((const unsigned*)Yb, A, Bact, csr, offs, deg, b1, bn1g, bn1b, bn1m, bn1v, N);
  // GCN 2 (residual Bact), out A
  k_gemm_mfma<<<gblk, 256, 0, stream>>>(Bact, Wb2, Yb, N, deg);
  k_gcn_agg<<<ablk, 256, 0, stream>>>((const unsigned*)Yb, Bact, A, csr, offs, deg, b2, bn2g, bn2b, bn2m, bn2v, N);
  // GCN 3 (no residual), out Bact
  k_gemm_mfma<<<gblk, 256, 0, stream>>>(A, Wb3, Yb, N, deg);
  k_gcn_agg<<<ablk, 256, 0, stream>>>((const unsigned*)Yb, nullptr, Bact, csr, offs, deg, b3, bn3g, bn3b, bn3m, bn3v, N);

  // pool + head
  k_pool<<<NG, 128, 0, stream>>>(Bact, batch, G, N);
  k_mlp<<<NG, 128, 0, stream>>>(G, p1w, p1b, p2w, p2b, cw, cb, (float*)d_out, NG);
}

// Round 4
// 735.518 us; speedup vs baseline: 1.5411x; 1.0472x over previous
//
#include <hip/hip_runtime.h>
#include <math.h>

#define BN_EPS 1e-5f
#define NPASS 4
typedef unsigned short u16;
typedef __attribute__((ext_vector_type(8))) short bf16x8;
typedef __attribute__((ext_vector_type(4))) float f32x4;

// ---------- bf16 helpers ----------
__device__ inline unsigned bfpack2(float a, float b){
  unsigned ua = __float_as_uint(a); ua = (ua + 0x7fffu + ((ua >> 16) & 1u)) >> 16;
  unsigned ub = __float_as_uint(b); ub = (ub + 0x7fffu + ((ub >> 16) & 1u)) >> 16;
  return ua | (ub << 16);
}
__device__ inline u16 bf16of(float a){
  unsigned ua = __float_as_uint(a); return (u16)((ua + 0x7fffu + ((ua >> 16) & 1u)) >> 16);
}
__device__ inline float bflo(unsigned u){ return __uint_as_float(u << 16); }
__device__ inline float bfhi(unsigned u){ return __uint_as_float(u & 0xffff0000u); }

// ---------------- preprocessing: CSR by dst ----------------
__global__ void k_count(const int* __restrict__ ei, int E, int N, int* __restrict__ deg){
  int e = blockIdx.x*256 + threadIdx.x;
  int ET = E + N;
  if (e >= ET) return;
  int dst = (e < E) ? ei[E + e] : (e - E);
  atomicAdd(&deg[dst], 1);
}

__global__ __launch_bounds__(1024) void k_scan_block(const int* __restrict__ deg, int* __restrict__ offs,
                                                     int* __restrict__ part, int N){
  __shared__ int sh[1024];
  int t = threadIdx.x; int i = blockIdx.x*1024 + t;
  int v = (i < N) ? deg[i] : 0;
  sh[t] = v; __syncthreads();
  for (int off = 1; off < 1024; off <<= 1){
    int u = (t >= off) ? sh[t - off] : 0;
    __syncthreads();
    sh[t] += u;
    __syncthreads();
  }
  if (i < N) offs[i] = sh[t] - v;
  if (t == 1023) part[blockIdx.x] = sh[1023];
}

__global__ void k_scan_part(int* part, int nb){
  if (threadIdx.x == 0 && blockIdx.x == 0){
    int s = 0;
    for (int i = 0; i < nb; ++i){ int v = part[i]; part[i] = s; s += v; }
  }
}

__global__ void k_add_part(int* __restrict__ offs, const int* __restrict__ part, int N){
  int i = blockIdx.x*256 + threadIdx.x;
  if (i < N) offs[i] += part[i >> 10];
}

// dst-range passes: pass p handles dst in [p*chunk, (p+1)*chunk) so the csr write
// window is ~1.7MB (L2-resident) instead of 6.8MB -> dense line eviction.
__global__ void k_fill(const int* __restrict__ ei, int E, int N, const int* __restrict__ offs,
                       int* __restrict__ cursor, int* __restrict__ csr, int blocksPerPass){
  int pass = blockIdx.x / blocksPerPass;
  int e = (blockIdx.x - pass*blocksPerPass)*256 + threadIdx.x;
  int ET = E + N;
  if (e >= ET) return;
  int chunk = (N + NPASS - 1) / NPASS;
  int lo = pass * chunk, hi = lo + chunk; if (hi > N) hi = N;
  int src, dst;
  if (e < E){
    dst = ei[E + e];
    if (dst < lo || dst >= hi) return;
    src = ei[e];
  } else {
    src = e - E; dst = src;
    if (dst < lo || dst >= hi) return;
  }
  int pos = offs[dst] + atomicAdd(&cursor[dst], 1);
  csr[pos] = src;
}

// ---------------- weight convert: WbT[n][k] = bf16(W[k][n]) ----------------
__global__ void k_wconv(const float* __restrict__ W, u16* __restrict__ WbT){
  int id = blockIdx.x*256 + threadIdx.x;   // 16384
  int nn = id >> 7, kk = id & 127;
  WbT[id] = bf16of(W[kk*128 + nn]);
}

// ---------------- MFMA GEMM: Yb[M x 128](bf16) = bf16(A[M x 128]) @ WbT^T, row scale rsqrt(deg) ----------------
__global__ __launch_bounds__(256, 2) void k_gemm_mfma(const float* __restrict__ A,
                                                      const u16* __restrict__ WbT,
                                                      u16* __restrict__ Yb, int M,
                                                      const int* __restrict__ deg){
  int lane = threadIdx.x & 63;
  int wv   = threadIdx.x >> 6;
  int row0 = blockIdx.x * 64 + wv * 16;       // 16 rows per wave
  int rA   = row0 + (lane & 15);
  if (rA >= M) rA = M - 1;
  int g    = lane >> 4;

  bf16x8 afr[4];
  const float* ap = A + (size_t)rA*128 + g*8;
  #pragma unroll
  for (int s = 0; s < 4; ++s){
    float4 f0 = *(const float4*)(ap + s*32);
    float4 f1 = *(const float4*)(ap + s*32 + 4);
    union { bf16x8 v; unsigned u[4]; } tmp;
    tmp.u[0] = bfpack2(f0.x, f0.y);
    tmp.u[1] = bfpack2(f0.z, f0.w);
    tmp.u[2] = bfpack2(f1.x, f1.y);
    tmp.u[3] = bfpack2(f1.z, f1.w);
    afr[s] = tmp.v;
  }

  f32x4 acc[8] = {};
  #pragma unroll
  for (int s = 0; s < 4; ++s){
    union BU { uint4 q; bf16x8 v; } b[8];
    #pragma unroll
    for (int t = 0; t < 8; ++t){
      int col = t*16 + (lane & 15);
      b[t].q = ((const uint4*)(WbT + (size_t)col*128))[s*4 + g];
    }
    #pragma unroll
    for (int t = 0; t < 8; ++t)
      acc[t] = __builtin_amdgcn_mfma_f32_16x16x32_bf16(afr[s], b[t].v, acc[t], 0, 0, 0);
  }

  int orow = row0 + (lane >> 4)*4;
  #pragma unroll
  for (int j = 0; j < 4; ++j){
    int r = orow + j;
    if (r < M){
      float sc = deg ? rsqrtf((float)deg[r]) : 1.0f;
      #pragma unroll
      for (int t = 0; t < 8; ++t)
        Yb[(size_t)r*128 + t*16 + (lane & 15)] = bf16of(acc[t][j] * sc);
    }
  }
}

// ---------------- GAT: per-node attention logits ----------------
__global__ __launch_bounds__(256) void k_attn(const unsigned* __restrict__ Yb, const float* __restrict__ asrcw,
                                              const float* __restrict__ adstw,
                                              float* __restrict__ a_src, float* __restrict__ a_dst, int N){
  int n = (blockIdx.x*256 + threadIdx.x) >> 6;
  int lane = threadIdx.x & 63;
  if (n >= N) return;
  int head = lane >> 4;
  int d0 = (lane & 15) * 2;
  unsigned u = Yb[(size_t)n*64 + lane];
  float h0 = bflo(u), h1 = bfhi(u);
  float vs = h0 * asrcw[head*32 + d0] + h1 * asrcw[head*32 + d0 + 1];
  float vd = h0 * adstw[head*32 + d0] + h1 * adstw[head*32 + d0 + 1];
  #pragma unroll
  for (int m = 1; m < 16; m <<= 1){
    vs += __shfl_xor(vs, m, 64);
    vd += __shfl_xor(vd, m, 64);
  }
  if ((lane & 15) == 0){
    a_src[n*4 + head] = vs;
    a_dst[n*4 + head] = vd;
  }
}

// ---------------- edge weights: 16-lane group per node (dst implicit -> no csrd) ----------------
__global__ __launch_bounds__(256) void k_edge_w(const int* __restrict__ csr, const int* __restrict__ offs,
                                                const int* __restrict__ deg,
                                                const float4* __restrict__ asrc4, const float4* __restrict__ adst4,
                                                float4* __restrict__ wE, int N){
  int n = blockIdx.x*16 + (threadIdx.x >> 4);
  int l16 = threadIdx.x & 15;
  if (n >= N) return;
  int beg = offs[n], d = deg[n];
  float4 ad = adst4[n];
  for (int i = l16; i < d; i += 16){
    float4 as = asrc4[csr[beg + i]];
    float e0 = as.x + ad.x; e0 = e0 > 0.f ? e0 : 0.2f*e0;
    float e1 = as.y + ad.y; e1 = e1 > 0.f ? e1 : 0.2f*e1;
    float e2 = as.z + ad.z; e2 = e2 > 0.f ? e2 : 0.2f*e2;
    float e3 = as.w + ad.w; e3 = e3 > 0.f ? e3 : 0.2f*e3;
    wE[beg + i] = make_float4(__expf(e0), __expf(e1), __expf(e2), __expf(e3));
  }
}

// ---------------- GAT aggregation: pure weighted gather, wave per node ----------------
__global__ __launch_bounds__(256) void k_gat_agg(const unsigned* __restrict__ Yb, const int* __restrict__ csr,
                                                 const int* __restrict__ offs, const int* __restrict__ deg,
                                                 const float* __restrict__ wE, const float* __restrict__ bias,
                                                 float* __restrict__ out, int N){
  int n = (blockIdx.x*256 + threadIdx.x) >> 6;
  int lane = threadIdx.x & 63;
  if (n >= N) return;
  int head = lane >> 4;
  int beg = offs[n], d = deg[n];
  const int* cp = csr + beg;
  const float* wp = wE + (size_t)beg*4 + head;
  float accx = 0.f, accy = 0.f, sw = 0.f;
  int i = 0;
  for (; i + 4 <= d; i += 4){
    int n0 = cp[i], n1 = cp[i+1], n2 = cp[i+2], n3 = cp[i+3];
    float w0 = wp[i*4], w1 = wp[i*4+4], w2 = wp[i*4+8], w3 = wp[i*4+12];
    unsigned v0 = Yb[(size_t)n0*64+lane], v1 = Yb[(size_t)n1*64+lane],
             v2 = Yb[(size_t)n2*64+lane], v3 = Yb[(size_t)n3*64+lane];
    accx += w0*bflo(v0) + w1*bflo(v1) + w2*bflo(v2) + w3*bflo(v3);
    accy += w0*bfhi(v0) + w1*bfhi(v1) + w2*bfhi(v2) + w3*bfhi(v3);
    sw   += (w0 + w1) + (w2 + w3);
  }
  for (; i < d; ++i){
    int sn = cp[i];
    float w = wp[i*4];
    unsigned v = Yb[(size_t)sn*64 + lane];
    accx += w * bflo(v);
    accy += w * bfhi(v);
    sw   += w;
  }
  float inv = 1.f / sw;
  float2 b = ((const float2*)bias)[lane];
  float z0 = accx*inv + b.x, z1 = accy*inv + b.y;
  z0 = z0 > 0.f ? z0 : expm1f(z0);
  z1 = z1 > 0.f ? z1 : expm1f(z1);
  ((float2*)out)[(size_t)n*64 + lane] = make_float2(z0, z1);
}

// ---------------- GCN aggregation + folded BN + ELU + residual ----------------
__global__ __launch_bounds__(256) void k_gcn_agg(const unsigned* __restrict__ Yb, const float* __restrict__ resid,
                                                 float* __restrict__ out, const int* __restrict__ csr,
                                                 const int* __restrict__ offs, const int* __restrict__ deg,
                                                 const float* __restrict__ gb, const float* __restrict__ bg,
                                                 const float* __restrict__ bb, const float* __restrict__ bm,
                                                 const float* __restrict__ bv, int N){
  int n = (blockIdx.x*256 + threadIdx.x) >> 6;
  int lane = threadIdx.x & 63;
  if (n >= N) return;
  int beg = offs[n], d = deg[n];
  const int* cp = csr + beg;
  float ax = 0.f, ay = 0.f;
  int i = 0;
  for (; i + 4 <= d; i += 4){
    int s0 = cp[i], s1 = cp[i+1], s2 = cp[i+2], s3 = cp[i+3];
    unsigned v0 = Yb[(size_t)s0*64+lane], v1 = Yb[(size_t)s1*64+lane],
             v2 = Yb[(size_t)s2*64+lane], v3 = Yb[(size_t)s3*64+lane];
    ax += (bflo(v0) + bflo(v1)) + (bflo(v2) + bflo(v3));
    ay += (bfhi(v0) + bfhi(v1)) + (bfhi(v2) + bfhi(v3));
  }
  for (; i < d; ++i){
    int sc = cp[i];
    unsigned v = Yb[(size_t)sc*64 + lane];
    ax += bflo(v); ay += bfhi(v);
  }
  float dinv = rsqrtf((float)d);
  float2 g  = ((const float2*)bg)[lane];
  float2 b  = ((const float2*)bb)[lane];
  float2 mm = ((const float2*)bm)[lane];
  float2 vv = ((const float2*)bv)[lane];
  float2 gb2 = ((const float2*)gb)[lane];
  float A0 = g.x * rsqrtf(vv.x + BN_EPS), A1 = g.y * rsqrtf(vv.y + BN_EPS);
  float z0 = ax*dinv*A0 + (gb2.x - mm.x)*A0 + b.x;
  float z1 = ay*dinv*A1 + (gb2.y - mm.y)*A1 + b.y;
  z0 = z0 > 0.f ? z0 : expm1f(z0);
  z1 = z1 > 0.f ? z1 : expm1f(z1);
  if (resid){
    float2 r = ((const float2*)resid)[(size_t)n*64 + lane];
    z0 += r.x; z1 += r.y;
  }
  ((float2*)out)[(size_t)n*64 + lane] = make_float2(z0, z1);
}

// ---------------- mean pool per graph (batch sorted) ----------------
__global__ __launch_bounds__(128) void k_pool(const float* __restrict__ H, const int* __restrict__ batch,
                                              float* __restrict__ G, int N){
  int gid = blockIdx.x; int c = threadIdx.x;
  int lo = 0, hi = N;
  while (lo < hi){ int mid = (lo + hi) >> 1; if (batch[mid] < gid) lo = mid + 1; else hi = mid; }
  int start = lo;
  lo = start; hi = N;
  while (lo < hi){ int mid = (lo + hi) >> 1; if (batch[mid] < gid + 1) lo = mid + 1; else hi = mid; }
  int end = lo;
  float acc = 0.f;
  for (int r = start; r < end; ++r) acc += H[(size_t)r*128 + c];
  float cnt = (float)(end - start);
  G[gid*128 + c] = acc / fmaxf(cnt, 1.0f);
}

// ---------------- MLP head ----------------
__global__ __launch_bounds__(128) void k_mlp(const float* __restrict__ G, const float* __restrict__ p1w,
                                             const float* __restrict__ p1b, const float* __restrict__ p2w,
                                             const float* __restrict__ p2b, const float* __restrict__ cw,
                                             const float* __restrict__ cb, float* __restrict__ out, int NG){
  int gid = blockIdx.x; int t = threadIdx.x;
  __shared__ float gv[128], t1[128], e[64];
  gv[t] = G[gid*128 + t];
  __syncthreads();
  float acc = p1b[t];
  for (int k = 0; k < 128; ++k) acc += gv[k] * p1w[k*128 + t];
  t1[t] = acc > 0.f ? acc : expm1f(acc);
  __syncthreads();
  if (t < 64){
    float a = p2b[t];
    for (int k = 0; k < 128; ++k) a += t1[k] * p2w[k*64 + t];
    e[t] = a;
    out[NG*3 + gid*64 + t] = a;
  }
  __syncthreads();
  if (t < 3){
    float a = cb[t];
    for (int k = 0; k < 64; ++k) a += e[k] * cw[k*3 + t];
    out[gid*3 + t] = a;
  }
}

extern "C" void kernel_launch(void* const* d_in, const int* in_sizes, int n_in,
                              void* d_out, int out_size, void* d_ws, size_t ws_size,
                              hipStream_t stream){
  const float* x      = (const float*)d_in[0];
  const int*   ei     = (const int*)d_in[1];
  const int*   batch  = (const int*)d_in[3];
  const float* gat_w  = (const float*)d_in[4];
  const float* att_s  = (const float*)d_in[5];
  const float* att_d  = (const float*)d_in[6];
  const float* gat_b  = (const float*)d_in[7];
  const float* w1 = (const float*)d_in[8];  const float* b1 = (const float*)d_in[9];
  const float* bn1g = (const float*)d_in[10], *bn1b = (const float*)d_in[11],
             * bn1m = (const float*)d_in[12], *bn1v = (const float*)d_in[13];
  const float* w2 = (const float*)d_in[14]; const float* b2 = (const float*)d_in[15];
  const float* bn2g = (const float*)d_in[16], *bn2b = (const float*)d_in[17],
             * bn2m = (const float*)d_in[18], *bn2v = (const float*)d_in[19];
  const float* w3 = (const float*)d_in[20]; const float* b3 = (const float*)d_in[21];
  const float* bn3g = (const float*)d_in[22], *bn3b = (const float*)d_in[23],
             * bn3m = (const float*)d_in[24], *bn3v = (const float*)d_in[25];
  const float* p1w = (const float*)d_in[26]; const float* p1b = (const float*)d_in[27];
  const float* p2w = (const float*)d_in[28]; const float* p2b = (const float*)d_in[29];
  const float* cw  = (const float*)d_in[30]; const float* cb  = (const float*)d_in[31];

  int N  = in_sizes[3];
  int E  = in_sizes[1] / 2;
  int ET = E + N;
  int NG = out_size / 67;

  char* ws = (char*)d_ws;
  size_t off = 0;
  auto alloc = [&](size_t bytes) -> void* {
    void* p = ws + off;
    off = (off + bytes + 255) & ~(size_t)255;
    return p;
  };
  float*    A    = (float*)alloc((size_t)N * 128 * 4);
  float*    Bact = (float*)alloc((size_t)N * 128 * 4);
  u16*      Yb   = (u16*)alloc((size_t)N * 128 * 2);
  int*      csr  = (int*)alloc((size_t)ET * 4);
  int*      deg  = (int*)alloc((size_t)N * 4);
  int*      offs = (int*)alloc((size_t)N * 4);
  int*      curs = (int*)alloc((size_t)N * 4);
  int*      part = (int*)alloc(1024 * 4);
  float*    asrc = (float*)alloc((size_t)N * 4 * 4);
  float*    adst = (float*)alloc((size_t)N * 4 * 4);
  float*    wE   = (float*)alloc((size_t)ET * 4 * 4);
  float*    G    = (float*)alloc((size_t)NG * 128 * 4);
  u16*      WbG  = (u16*)alloc(16384 * 2);
  u16*      Wb1  = (u16*)alloc(16384 * 2);
  u16*      Wb2  = (u16*)alloc(16384 * 2);
  u16*      Wb3  = (u16*)alloc(16384 * 2);

  hipMemsetAsync(deg,  0, (size_t)N * 4, stream);
  hipMemsetAsync(curs, 0, (size_t)N * 4, stream);

  int nb = (N + 1023) / 1024;
  k_count<<<(ET + 255)/256, 256, 0, stream>>>(ei, E, N, deg);
  k_scan_block<<<nb, 1024, 0, stream>>>(deg, offs, part, N);
  k_scan_part<<<1, 1, 0, stream>>>(part, nb);
  k_add_part<<<(N + 255)/256, 256, 0, stream>>>(offs, part, N);
  int bpp = (ET + 255)/256;
  k_fill<<<NPASS*bpp, 256, 0, stream>>>(ei, E, N, offs, curs, csr, bpp);

  k_wconv<<<64, 256, 0, stream>>>(gat_w, WbG);
  k_wconv<<<64, 256, 0, stream>>>(w1, Wb1);
  k_wconv<<<64, 256, 0, stream>>>(w2, Wb2);
  k_wconv<<<64, 256, 0, stream>>>(w3, Wb3);

  int gblk = (N + 63) / 64;
  int ablk = (N + 3) / 4;

  // GAT
  k_gemm_mfma<<<gblk, 256, 0, stream>>>(x, WbG, Yb, N, nullptr);
  k_attn<<<ablk, 256, 0, stream>>>((const unsigned*)Yb, att_s, att_d, asrc, adst, N);
  k_edge_w<<<(N + 15)/16, 256, 0, stream>>>(csr, offs, deg, (const float4*)asrc, (const float4*)adst,
                                            (float4*)wE, N);
  k_gat_agg<<<ablk, 256, 0, stream>>>((const unsigned*)Yb, csr, offs, deg, wE, gat_b, A, N);

  // GCN 1 (residual A), out Bact
  k_gemm_mfma<<<gblk, 256, 0, stream>>>(A, Wb1, Yb, N, deg);
  k_gcn_agg<<<ablk, 256, 0, stream>>>((const unsigned*)Yb, A, Bact, csr, offs, deg, b1, bn1g, bn1b, bn1m, bn1v, N);
  // GCN 2 (residual Bact), out A
  k_gemm_mfma<<<gblk, 256, 0, stream>>>(Bact, Wb2, Yb, N, deg);
  k_gcn_agg<<<ablk, 256, 0, stream>>>((const unsigned*)Yb, Bact, A, csr, offs, deg, b2, bn2g, bn2b, bn2m, bn2v, N);
  // GCN 3 (no residual), out Bact
  k_gemm_mfma<<<gblk, 256, 0, stream>>>(A, Wb3, Yb, N, deg);
  k_gcn_agg<<<ablk, 256, 0, stream>>>((const unsigned*)Yb, nullptr, Bact, csr, offs, deg, b3, bn3g, bn3b, bn3m, bn3v, N);

  // pool + head
  k_pool<<<NG, 128, 0, stream>>>(Bact, batch, G, N);
  k_mlp<<<NG, 128, 0, stream>>>(G, p1w, p1b, p2w, p2b, cw, cb, (float*)d_out, NG);
}

// Round 5
// 676.436 us; speedup vs baseline: 1.6757x; 1.0873x over previous
//
#include <hip/hip_runtime.h>
#include <math.h>

#define BN_EPS 1e-5f
#define NPASS 4
typedef unsigned short u16;
typedef __attribute__((ext_vector_type(8))) short bf16x8;
typedef __attribute__((ext_vector_type(4))) float f32x4;

// ---------- bf16 helpers ----------
__device__ inline unsigned bfpack2(float a, float b){
  unsigned ua = __float_as_uint(a); ua = (ua + 0x7fffu + ((ua >> 16) & 1u)) >> 16;
  unsigned ub = __float_as_uint(b); ub = (ub + 0x7fffu + ((ub >> 16) & 1u)) >> 16;
  return ua | (ub << 16);
}
__device__ inline u16 bf16of(float a){
  unsigned ua = __float_as_uint(a); return (u16)((ua + 0x7fffu + ((ua >> 16) & 1u)) >> 16);
}
__device__ inline float bflo(unsigned u){ return __uint_as_float(u << 16); }
__device__ inline float bfhi(unsigned u){ return __uint_as_float(u & 0xffff0000u); }

// ---------------- preprocessing: CSR by dst ----------------
__global__ void k_count(const int* __restrict__ ei, int E, int N, int* __restrict__ deg){
  int e = blockIdx.x*256 + threadIdx.x;
  int ET = E + N;
  if (e >= ET) return;
  int dst = (e < E) ? ei[E + e] : (e - E);
  atomicAdd(&deg[dst], 1);
}

__global__ __launch_bounds__(1024) void k_scan_block(const int* __restrict__ deg, int* __restrict__ offs,
                                                     int* __restrict__ part, int N){
  __shared__ int sh[1024];
  int t = threadIdx.x; int i = blockIdx.x*1024 + t;
  int v = (i < N) ? deg[i] : 0;
  sh[t] = v; __syncthreads();
  for (int off = 1; off < 1024; off <<= 1){
    int u = (t >= off) ? sh[t - off] : 0;
    __syncthreads();
    sh[t] += u;
    __syncthreads();
  }
  if (i < N) offs[i] = sh[t] - v;
  if (t == 1023) part[blockIdx.x] = sh[1023];
}

__global__ void k_scan_part(int* part, int nb){
  if (threadIdx.x == 0 && blockIdx.x == 0){
    int s = 0;
    for (int i = 0; i < nb; ++i){ int v = part[i]; part[i] = s; s += v; }
  }
}

__global__ void k_add_part(int* __restrict__ offs, const int* __restrict__ part, int N){
  int i = blockIdx.x*256 + threadIdx.x;
  if (i < N) offs[i] += part[i >> 10];
}

__global__ void k_fill(const int* __restrict__ ei, int E, int N, const int* __restrict__ offs,
                       int* __restrict__ cursor, int* __restrict__ csr, int blocksPerPass){
  int pass = blockIdx.x / blocksPerPass;
  int e = (blockIdx.x - pass*blocksPerPass)*256 + threadIdx.x;
  int ET = E + N;
  if (e >= ET) return;
  int chunk = (N + NPASS - 1) / NPASS;
  int lo = pass * chunk, hi = lo + chunk; if (hi > N) hi = N;
  int src, dst;
  if (e < E){
    dst = ei[E + e];
    if (dst < lo || dst >= hi) return;
    src = ei[e];
  } else {
    src = e - E; dst = src;
    if (dst < lo || dst >= hi) return;
  }
  int pos = offs[dst] + atomicAdd(&cursor[dst], 1);
  csr[pos] = src;
}

// ---------------- weight convert: WbT[n][k] = bf16(W[k][n]) ----------------
__global__ void k_wconv(const float* __restrict__ W, u16* __restrict__ WbT){
  int id = blockIdx.x*256 + threadIdx.x;   // 16384
  int nn = id >> 7, kk = id & 127;
  WbT[id] = bf16of(W[kk*128 + nn]);
}

// ---------------- MFMA GEMM: Yb[M x 128](bf16) = bf16(A[M x 128]) @ WbT^T, row scale rsqrt(deg) ----------------
__global__ __launch_bounds__(256, 2) void k_gemm_mfma(const float* __restrict__ A,
                                                      const u16* __restrict__ WbT,
                                                      u16* __restrict__ Yb, int M,
                                                      const int* __restrict__ deg){
  int lane = threadIdx.x & 63;
  int wv   = threadIdx.x >> 6;
  int row0 = blockIdx.x * 64 + wv * 16;
  int rA   = row0 + (lane & 15);
  if (rA >= M) rA = M - 1;
  int g    = lane >> 4;

  bf16x8 afr[4];
  const float* ap = A + (size_t)rA*128 + g*8;
  #pragma unroll
  for (int s = 0; s < 4; ++s){
    float4 f0 = *(const float4*)(ap + s*32);
    float4 f1 = *(const float4*)(ap + s*32 + 4);
    union { bf16x8 v; unsigned u[4]; } tmp;
    tmp.u[0] = bfpack2(f0.x, f0.y);
    tmp.u[1] = bfpack2(f0.z, f0.w);
    tmp.u[2] = bfpack2(f1.x, f1.y);
    tmp.u[3] = bfpack2(f1.z, f1.w);
    afr[s] = tmp.v;
  }

  f32x4 acc[8] = {};
  #pragma unroll
  for (int s = 0; s < 4; ++s){
    union BU { uint4 q; bf16x8 v; } b[8];
    #pragma unroll
    for (int t = 0; t < 8; ++t){
      int col = t*16 + (lane & 15);
      b[t].q = ((const uint4*)(WbT + (size_t)col*128))[s*4 + g];
    }
    #pragma unroll
    for (int t = 0; t < 8; ++t)
      acc[t] = __builtin_amdgcn_mfma_f32_16x16x32_bf16(afr[s], b[t].v, acc[t], 0, 0, 0);
  }

  int orow = row0 + (lane >> 4)*4;
  #pragma unroll
  for (int j = 0; j < 4; ++j){
    int r = orow + j;
    if (r < M){
      float sc = deg ? rsqrtf((float)deg[r]) : 1.0f;
      #pragma unroll
      for (int t = 0; t < 8; ++t)
        Yb[(size_t)r*128 + t*16 + (lane & 15)] = bf16of(acc[t][j] * sc);
    }
  }
}

// ---------------- GAT: per-node attention logits ----------------
__global__ __launch_bounds__(256) void k_attn(const unsigned* __restrict__ Yb, const float* __restrict__ asrcw,
                                              const float* __restrict__ adstw,
                                              float* __restrict__ a_src, float* __restrict__ a_dst, int N){
  int n = (blockIdx.x*256 + threadIdx.x) >> 6;
  int lane = threadIdx.x & 63;
  if (n >= N) return;
  int head = lane >> 4;
  int d0 = (lane & 15) * 2;
  unsigned u = Yb[(size_t)n*64 + lane];
  float h0 = bflo(u), h1 = bfhi(u);
  float vs = h0 * asrcw[head*32 + d0] + h1 * asrcw[head*32 + d0 + 1];
  float vd = h0 * adstw[head*32 + d0] + h1 * adstw[head*32 + d0 + 1];
  #pragma unroll
  for (int m = 1; m < 16; m <<= 1){
    vs += __shfl_xor(vs, m, 64);
    vd += __shfl_xor(vd, m, 64);
  }
  if ((lane & 15) == 0){
    a_src[n*4 + head] = vs;
    a_dst[n*4 + head] = vd;
  }
}

// ---------------- edge weights: 16-lane group per node ----------------
__global__ __launch_bounds__(256) void k_edge_w(const int* __restrict__ csr, const int* __restrict__ offs,
                                                const int* __restrict__ deg,
                                                const float4* __restrict__ asrc4, const float4* __restrict__ adst4,
                                                float4* __restrict__ wE, int N){
  int n = blockIdx.x*16 + (threadIdx.x >> 4);
  int l16 = threadIdx.x & 15;
  if (n >= N) return;
  int beg = offs[n], d = deg[n];
  float4 ad = adst4[n];
  for (int i = l16; i < d; i += 16){
    float4 as = asrc4[csr[beg + i]];
    float e0 = as.x + ad.x; e0 = e0 > 0.f ? e0 : 0.2f*e0;
    float e1 = as.y + ad.y; e1 = e1 > 0.f ? e1 : 0.2f*e1;
    float e2 = as.z + ad.z; e2 = e2 > 0.f ? e2 : 0.2f*e2;
    float e3 = as.w + ad.w; e3 = e3 > 0.f ? e3 : 0.2f*e3;
    wE[beg + i] = make_float4(__expf(e0), __expf(e1), __expf(e2), __expf(e3));
  }
}

// ---------------- GAT aggregation: 16 lanes/node, uint4 gathers (4 nodes per wave) ----------------
__global__ __launch_bounds__(256) void k_gat_agg(const uint4* __restrict__ Yb4, const int* __restrict__ csr,
                                                 const int* __restrict__ offs, const int* __restrict__ deg,
                                                 const float* __restrict__ wE, const float* __restrict__ bias,
                                                 float* __restrict__ out, int N){
  int n = blockIdx.x*16 + (threadIdx.x >> 4);
  int l = threadIdx.x & 15;            // 8 channels per lane
  if (n >= N) return;
  int head = l >> 2;
  int beg = offs[n], d = deg[n];
  const int* cp = csr + beg;
  const float* wp = wE + (size_t)beg*4 + head;
  float a[8] = {};
  float sw = 0.f;
  for (int i = 0; i < d; i += 4){
    int j1 = (i+1 < d) ? i+1 : i;
    int j2 = (i+2 < d) ? i+2 : i;
    int j3 = (i+3 < d) ? i+3 : i;
    int n0 = cp[i], n1 = cp[j1], n2 = cp[j2], n3 = cp[j3];
    uint4 v0 = Yb4[(size_t)n0*16 + l];
    uint4 v1 = Yb4[(size_t)n1*16 + l];
    uint4 v2 = Yb4[(size_t)n2*16 + l];
    uint4 v3 = Yb4[(size_t)n3*16 + l];
    float w0 = wp[(size_t)i*4];
    float w1 = (i+1 < d) ? wp[(size_t)j1*4] : 0.f;
    float w2 = (i+2 < d) ? wp[(size_t)j2*4] : 0.f;
    float w3 = (i+3 < d) ? wp[(size_t)j3*4] : 0.f;
    sw += (w0 + w1) + (w2 + w3);
    unsigned u0[4] = {v0.x, v0.y, v0.z, v0.w};
    unsigned u1[4] = {v1.x, v1.y, v1.z, v1.w};
    unsigned u2[4] = {v2.x, v2.y, v2.z, v2.w};
    unsigned u3[4] = {v3.x, v3.y, v3.z, v3.w};
    #pragma unroll
    for (int c = 0; c < 4; ++c){
      a[2*c]   += w0*bflo(u0[c]) + w1*bflo(u1[c]) + w2*bflo(u2[c]) + w3*bflo(u3[c]);
      a[2*c+1] += w0*bfhi(u0[c]) + w1*bfhi(u1[c]) + w2*bfhi(u2[c]) + w3*bfhi(u3[c]);
    }
  }
  float inv = 1.f / sw;
  int c0 = l*8;
  float4 b0 = *(const float4*)(bias + c0);
  float4 b1 = *(const float4*)(bias + c0 + 4);
  float bb8[8] = {b0.x,b0.y,b0.z,b0.w,b1.x,b1.y,b1.z,b1.w};
  float og[8];
  #pragma unroll
  for (int c = 0; c < 8; ++c){
    float z = a[c]*inv + bb8[c];
    og[c] = z > 0.f ? z : expm1f(z);
  }
  float* op = out + (size_t)n*128 + c0;
  *(float4*)op       = make_float4(og[0],og[1],og[2],og[3]);
  *(float4*)(op + 4) = make_float4(og[4],og[5],og[6],og[7]);
}

// ---------------- GCN aggregation + folded BN + ELU + residual: 16 lanes/node, uint4 gathers ----------------
__global__ __launch_bounds__(256) void k_gcn_agg(const uint4* __restrict__ Yb4, const float* __restrict__ resid,
                                                 float* __restrict__ out, const int* __restrict__ csr,
                                                 const int* __restrict__ offs, const int* __restrict__ deg,
                                                 const float* __restrict__ gb, const float* __restrict__ bg,
                                                 const float* __restrict__ bb, const float* __restrict__ bm,
                                                 const float* __restrict__ bv, int N){
  int n = blockIdx.x*16 + (threadIdx.x >> 4);
  int l = threadIdx.x & 15;
  if (n >= N) return;
  int beg = offs[n], d = deg[n];
  const int* cp = csr + beg;
  float a[8] = {};
  for (int i = 0; i < d; i += 4){
    int j1 = (i+1 < d) ? i+1 : i;
    int j2 = (i+2 < d) ? i+2 : i;
    int j3 = (i+3 < d) ? i+3 : i;
    int n0 = cp[i], n1 = cp[j1], n2 = cp[j2], n3 = cp[j3];
    uint4 v0 = Yb4[(size_t)n0*16 + l];
    uint4 v1 = Yb4[(size_t)n1*16 + l];
    uint4 v2 = Yb4[(size_t)n2*16 + l];
    uint4 v3 = Yb4[(size_t)n3*16 + l];
    float m1 = (i+1 < d) ? 1.f : 0.f;
    float m2 = (i+2 < d) ? 1.f : 0.f;
    float m3 = (i+3 < d) ? 1.f : 0.f;
    unsigned u0[4] = {v0.x, v0.y, v0.z, v0.w};
    unsigned u1[4] = {v1.x, v1.y, v1.z, v1.w};
    unsigned u2[4] = {v2.x, v2.y, v2.z, v2.w};
    unsigned u3[4] = {v3.x, v3.y, v3.z, v3.w};
    #pragma unroll
    for (int c = 0; c < 4; ++c){
      a[2*c]   += bflo(u0[c]) + m1*bflo(u1[c]) + m2*bflo(u2[c]) + m3*bflo(u3[c]);
      a[2*c+1] += bfhi(u0[c]) + m1*bfhi(u1[c]) + m2*bfhi(u2[c]) + m3*bfhi(u3[c]);
    }
  }
  float dinv = rsqrtf((float)d);
  int c0 = l*8;
  float4 g0  = *(const float4*)(bg + c0),  g1  = *(const float4*)(bg + c0 + 4);
  float4 bb0 = *(const float4*)(bb + c0),  bb1 = *(const float4*)(bb + c0 + 4);
  float4 m0  = *(const float4*)(bm + c0),  m1v = *(const float4*)(bm + c0 + 4);
  float4 v0  = *(const float4*)(bv + c0),  v1  = *(const float4*)(bv + c0 + 4);
  float4 q0  = *(const float4*)(gb + c0),  q1  = *(const float4*)(gb + c0 + 4);
  float gg[8]  = {g0.x,g0.y,g0.z,g0.w,g1.x,g1.y,g1.z,g1.w};
  float bbb[8] = {bb0.x,bb0.y,bb0.z,bb0.w,bb1.x,bb1.y,bb1.z,bb1.w};
  float mmm[8] = {m0.x,m0.y,m0.z,m0.w,m1v.x,m1v.y,m1v.z,m1v.w};
  float vvv[8] = {v0.x,v0.y,v0.z,v0.w,v1.x,v1.y,v1.z,v1.w};
  float qqq[8] = {q0.x,q0.y,q0.z,q0.w,q1.x,q1.y,q1.z,q1.w};
  float og[8];
  const float* rp = resid ? (resid + (size_t)n*128 + c0) : nullptr;
  float4 r0, r1;
  if (rp){ r0 = *(const float4*)rp; r1 = *(const float4*)(rp + 4); }
  float rr[8];
  if (rp){ rr[0]=r0.x; rr[1]=r0.y; rr[2]=r0.z; rr[3]=r0.w; rr[4]=r1.x; rr[5]=r1.y; rr[6]=r1.z; rr[7]=r1.w; }
  #pragma unroll
  for (int c = 0; c < 8; ++c){
    float As = gg[c] * rsqrtf(vvv[c] + BN_EPS);
    float z = a[c]*dinv*As + (qqq[c] - mmm[c])*As + bbb[c];
    z = z > 0.f ? z : expm1f(z);
    if (rp) z += rr[c];
    og[c] = z;
  }
  float* op = out + (size_t)n*128 + c0;
  *(float4*)op       = make_float4(og[0],og[1],og[2],og[3]);
  *(float4*)(op + 4) = make_float4(og[4],og[5],og[6],og[7]);
}

// ---------------- mean pool per graph (batch sorted) ----------------
__global__ __launch_bounds__(128) void k_pool(const float* __restrict__ H, const int* __restrict__ batch,
                                              float* __restrict__ G, int N){
  int gid = blockIdx.x; int c = threadIdx.x;
  int lo = 0, hi = N;
  while (lo < hi){ int mid = (lo + hi) >> 1; if (batch[mid] < gid) lo = mid + 1; else hi = mid; }
  int start = lo;
  lo = start; hi = N;
  while (lo < hi){ int mid = (lo + hi) >> 1; if (batch[mid] < gid + 1) lo = mid + 1; else hi = mid; }
  int end = lo;
  float acc = 0.f;
  for (int r = start; r < end; ++r) acc += H[(size_t)r*128 + c];
  float cnt = (float)(end - start);
  G[gid*128 + c] = acc / fmaxf(cnt, 1.0f);
}

// ---------------- MLP head ----------------
__global__ __launch_bounds__(128) void k_mlp(const float* __restrict__ G, const float* __restrict__ p1w,
                                             const float* __restrict__ p1b, const float* __restrict__ p2w,
                                             const float* __restrict__ p2b, const float* __restrict__ cw,
                                             const float* __restrict__ cb, float* __restrict__ out, int NG){
  int gid = blockIdx.x; int t = threadIdx.x;
  __shared__ float gv[128], t1[128], e[64];
  gv[t] = G[gid*128 + t];
  __syncthreads();
  float acc = p1b[t];
  for (int k = 0; k < 128; ++k) acc += gv[k] * p1w[k*128 + t];
  t1[t] = acc > 0.f ? acc : expm1f(acc);
  __syncthreads();
  if (t < 64){
    float a = p2b[t];
    for (int k = 0; k < 128; ++k) a += t1[k] * p2w[k*64 + t];
    e[t] = a;
    out[NG*3 + gid*64 + t] = a;
  }
  __syncthreads();
  if (t < 3){
    float a = cb[t];
    for (int k = 0; k < 64; ++k) a += e[k] * cw[k*3 + t];
    out[gid*3 + t] = a;
  }
}

extern "C" void kernel_launch(void* const* d_in, const int* in_sizes, int n_in,
                              void* d_out, int out_size, void* d_ws, size_t ws_size,
                              hipStream_t stream){
  const float* x      = (const float*)d_in[0];
  const int*   ei     = (const int*)d_in[1];
  const int*   batch  = (const int*)d_in[3];
  const float* gat_w  = (const float*)d_in[4];
  const float* att_s  = (const float*)d_in[5];
  const float* att_d  = (const float*)d_in[6];
  const float* gat_b  = (const float*)d_in[7];
  const float* w1 = (const float*)d_in[8];  const float* b1 = (const float*)d_in[9];
  const float* bn1g = (const float*)d_in[10], *bn1b = (const float*)d_in[11],
             * bn1m = (const float*)d_in[12], *bn1v = (const float*)d_in[13];
  const float* w2 = (const float*)d_in[14]; const float* b2 = (const float*)d_in[15];
  const float* bn2g = (const float*)d_in[16], *bn2b = (const float*)d_in[17],
             * bn2m = (const float*)d_in[18], *bn2v = (const float*)d_in[19];
  const float* w3 = (const float*)d_in[20]; const float* b3 = (const float*)d_in[21];
  const float* bn3g = (const float*)d_in[22], *bn3b = (const float*)d_in[23],
             * bn3m = (const float*)d_in[24], *bn3v = (const float*)d_in[25];
  const float* p1w = (const float*)d_in[26]; const float* p1b = (const float*)d_in[27];
  const float* p2w = (const float*)d_in[28]; const float* p2b = (const float*)d_in[29];
  const float* cw  = (const float*)d_in[30]; const float* cb  = (const float*)d_in[31];

  int N  = in_sizes[3];
  int E  = in_sizes[1] / 2;
  int ET = E + N;
  int NG = out_size / 67;

  char* ws = (char*)d_ws;
  size_t off = 0;
  auto alloc = [&](size_t bytes) -> void* {
    void* p = ws + off;
    off = (off + bytes + 255) & ~(size_t)255;
    return p;
  };
  float*    A    = (float*)alloc((size_t)N * 128 * 4);
  float*    Bact = (float*)alloc((size_t)N * 128 * 4);
  u16*      Yb   = (u16*)alloc((size_t)N * 128 * 2);
  int*      csr  = (int*)alloc((size_t)ET * 4);
  int*      deg  = (int*)alloc((size_t)N * 4);
  int*      offs = (int*)alloc((size_t)N * 4);
  int*      curs = (int*)alloc((size_t)N * 4);
  int*      part = (int*)alloc(1024 * 4);
  float*    asrc = (float*)alloc((size_t)N * 4 * 4);
  float*    adst = (float*)alloc((size_t)N * 4 * 4);
  float*    wE   = (float*)alloc((size_t)ET * 4 * 4);
  float*    G    = (float*)alloc((size_t)NG * 128 * 4);
  u16*      WbG  = (u16*)alloc(16384 * 2);
  u16*      Wb1  = (u16*)alloc(16384 * 2);
  u16*      Wb2  = (u16*)alloc(16384 * 2);
  u16*      Wb3  = (u16*)alloc(16384 * 2);

  hipMemsetAsync(deg,  0, (size_t)N * 4, stream);
  hipMemsetAsync(curs, 0, (size_t)N * 4, stream);

  int nb = (N + 1023) / 1024;
  k_count<<<(ET + 255)/256, 256, 0, stream>>>(ei, E, N, deg);
  k_scan_block<<<nb, 1024, 0, stream>>>(deg, offs, part, N);
  k_scan_part<<<1, 1, 0, stream>>>(part, nb);
  k_add_part<<<(N + 255)/256, 256, 0, stream>>>(offs, part, N);
  int bpp = (ET + 255)/256;
  k_fill<<<NPASS*bpp, 256, 0, stream>>>(ei, E, N, offs, curs, csr, bpp);

  k_wconv<<<64, 256, 0, stream>>>(gat_w, WbG);
  k_wconv<<<64, 256, 0, stream>>>(w1, Wb1);
  k_wconv<<<64, 256, 0, stream>>>(w2, Wb2);
  k_wconv<<<64, 256, 0, stream>>>(w3, Wb3);

  int gblk = (N + 63) / 64;
  int nblk16 = (N + 15) / 16;
  int ablk = (N + 3) / 4;

  // GAT
  k_gemm_mfma<<<gblk, 256, 0, stream>>>(x, WbG, Yb, N, nullptr);
  k_attn<<<ablk, 256, 0, stream>>>((const unsigned*)Yb, att_s, att_d, asrc, adst, N);
  k_edge_w<<<nblk16, 256, 0, stream>>>(csr, offs, deg, (const float4*)asrc, (const float4*)adst,
                                       (float4*)wE, N);
  k_gat_agg<<<nblk16, 256, 0, stream>>>((const uint4*)Yb, csr, offs, deg, wE, gat_b, A, N);

  // GCN 1 (residual A), out Bact
  k_gemm_mfma<<<gblk, 256, 0, stream>>>(A, Wb1, Yb, N, deg);
  k_gcn_agg<<<nblk16, 256, 0, stream>>>((const uint4*)Yb, A, Bact, csr, offs, deg, b1, bn1g, bn1b, bn1m, bn1v, N);
  // GCN 2 (residual Bact), out A
  k_gemm_mfma<<<gblk, 256, 0, stream>>>(Bact, Wb2, Yb, N, deg);
  k_gcn_agg<<<nblk16, 256, 0, stream>>>((const uint4*)Yb, Bact, A, csr, offs, deg, b2, bn2g, bn2b, bn2m, bn2v, N);
  // GCN 3 (no residual), out Bact
  k_gemm_mfma<<<gblk, 256, 0, stream>>>(A, Wb3, Yb, N, deg);
  k_gcn_agg<<<nblk16, 256, 0, stream>>>((const uint4*)Yb, nullptr, Bact, csr, offs, deg, b3, bn3g, bn3b, bn3m, bn3v, N);

  // pool + head
  k_pool<<<NG, 128, 0, stream>>>(Bact, batch, G, N);
  k_mlp<<<NG, 128, 0, stream>>>(G, p1w, p1b, p2w, p2b, cw, cb, (float*)d_out, NG);
}

// Round 6
// 666.585 us; speedup vs baseline: 1.7004x; 1.0148x over previous
//
#include <hip/hip_runtime.h>
#include <math.h>

#define BN_EPS 1e-5f
typedef unsigned short u16;
typedef __attribute__((ext_vector_type(8))) short bf16x8;
typedef __attribute__((ext_vector_type(4))) float f32x4;

// ---------- bf16 helpers ----------
__device__ inline unsigned bfpack2(float a, float b){
  unsigned ua = __float_as_uint(a); ua = (ua + 0x7fffu + ((ua >> 16) & 1u)) >> 16;
  unsigned ub = __float_as_uint(b); ub = (ub + 0x7fffu + ((ub >> 16) & 1u)) >> 16;
  return ua | (ub << 16);
}
__device__ inline u16 bf16of(float a){
  unsigned ua = __float_as_uint(a); return (u16)((ua + 0x7fffu + ((ua >> 16) & 1u)) >> 16);
}
__device__ inline float bflo(unsigned u){ return __uint_as_float(u << 16); }
__device__ inline float bfhi(unsigned u){ return __uint_as_float(u & 0xffff0000u); }

// ---------------- preprocessing: CSR by dst ----------------
// XCD-aware: chunk = blockIdx&7; blocks round-robin across XCDs, so all blocks of
// chunk c land on XCD c -> deg/csr lines for that dst range stay in ONE XCD's L2.
__global__ void k_count(const int* __restrict__ ei, int E, int N, int* __restrict__ deg){
  int chunk = blockIdx.x & 7;
  int e = (blockIdx.x >> 3)*256 + threadIdx.x;
  int ET = E + N;
  if (e >= ET) return;
  int csz = (N + 7) >> 3;
  int lo = chunk*csz, hi = lo + csz; if (hi > N) hi = N;
  int dst = (e < E) ? ei[E + e] : (e - E);
  if (dst < lo || dst >= hi) return;
  atomicAdd(&deg[dst], 1);
}

__global__ __launch_bounds__(1024) void k_scan_block(const int* __restrict__ deg, int* __restrict__ offs,
                                                     int* __restrict__ part, int N){
  __shared__ int sh[1024];
  int t = threadIdx.x; int i = blockIdx.x*1024 + t;
  int v = (i < N) ? deg[i] : 0;
  sh[t] = v; __syncthreads();
  for (int off = 1; off < 1024; off <<= 1){
    int u = (t >= off) ? sh[t - off] : 0;
    __syncthreads();
    sh[t] += u;
    __syncthreads();
  }
  if (i < N) offs[i] = sh[t] - v;
  if (t == 1023) part[blockIdx.x] = sh[1023];
}

__global__ void k_scan_part(int* part, int nb){
  if (threadIdx.x == 0 && blockIdx.x == 0){
    int s = 0;
    for (int i = 0; i < nb; ++i){ int v = part[i]; part[i] = s; s += v; }
  }
}

__global__ void k_add_part(int* __restrict__ offs, const int* __restrict__ part, int N){
  int i = blockIdx.x*256 + threadIdx.x;
  if (i < N) offs[i] += part[i >> 10];
}

// XCD-aware dst-chunk binding (see k_count comment): one XCD owns each csr range.
__global__ void k_fill(const int* __restrict__ ei, int E, int N, const int* __restrict__ offs,
                       int* __restrict__ cursor, int* __restrict__ csr){
  int chunk = blockIdx.x & 7;
  int e = (blockIdx.x >> 3)*256 + threadIdx.x;
  int ET = E + N;
  if (e >= ET) return;
  int csz = (N + 7) >> 3;
  int lo = chunk*csz, hi = lo + csz; if (hi > N) hi = N;
  int src, dst;
  if (e < E){
    dst = ei[E + e];
    if (dst < lo || dst >= hi) return;
    src = ei[e];
  } else {
    src = e - E; dst = src;
    if (dst < lo || dst >= hi) return;
  }
  int pos = offs[dst] + atomicAdd(&cursor[dst], 1);
  csr[pos] = src;
}

// ---------------- weight convert: WbT[n][k] = bf16(W[k][n]) ----------------
__global__ void k_wconv(const float* __restrict__ W, u16* __restrict__ WbT){
  int id = blockIdx.x*256 + threadIdx.x;   // 16384
  int nn = id >> 7, kk = id & 127;
  WbT[id] = bf16of(W[kk*128 + nn]);
}

// ---------------- MFMA GEMM: Yb[M x 128](bf16) = bf16(A[M x 128]) @ WbT^T, row scale rsqrt(deg) ----------------
__global__ __launch_bounds__(256, 2) void k_gemm_mfma(const float* __restrict__ A,
                                                      const u16* __restrict__ WbT,
                                                      u16* __restrict__ Yb, int M,
                                                      const int* __restrict__ deg){
  int lane = threadIdx.x & 63;
  int wv   = threadIdx.x >> 6;
  int row0 = blockIdx.x * 64 + wv * 16;
  int rA   = row0 + (lane & 15);
  if (rA >= M) rA = M - 1;
  int g    = lane >> 4;

  bf16x8 afr[4];
  const float* ap = A + (size_t)rA*128 + g*8;
  #pragma unroll
  for (int s = 0; s < 4; ++s){
    float4 f0 = *(const float4*)(ap + s*32);
    float4 f1 = *(const float4*)(ap + s*32 + 4);
    union { bf16x8 v; unsigned u[4]; } tmp;
    tmp.u[0] = bfpack2(f0.x, f0.y);
    tmp.u[1] = bfpack2(f0.z, f0.w);
    tmp.u[2] = bfpack2(f1.x, f1.y);
    tmp.u[3] = bfpack2(f1.z, f1.w);
    afr[s] = tmp.v;
  }

  f32x4 acc[8] = {};
  #pragma unroll
  for (int s = 0; s < 4; ++s){
    union BU { uint4 q; bf16x8 v; } b[8];
    #pragma unroll
    for (int t = 0; t < 8; ++t){
      int col = t*16 + (lane & 15);
      b[t].q = ((const uint4*)(WbT + (size_t)col*128))[s*4 + g];
    }
    #pragma unroll
    for (int t = 0; t < 8; ++t)
      acc[t] = __builtin_amdgcn_mfma_f32_16x16x32_bf16(afr[s], b[t].v, acc[t], 0, 0, 0);
  }

  int orow = row0 + (lane >> 4)*4;
  #pragma unroll
  for (int j = 0; j < 4; ++j){
    int r = orow + j;
    if (r < M){
      float sc = deg ? rsqrtf((float)deg[r]) : 1.0f;
      #pragma unroll
      for (int t = 0; t < 8; ++t)
        Yb[(size_t)r*128 + t*16 + (lane & 15)] = bf16of(acc[t][j] * sc);
    }
  }
}

// ---------------- GAT: per-node attention logits ----------------
__global__ __launch_bounds__(256) void k_attn(const unsigned* __restrict__ Yb, const float* __restrict__ asrcw,
                                              const float* __restrict__ adstw,
                                              float* __restrict__ a_src, float* __restrict__ a_dst, int N){
  int n = (blockIdx.x*256 + threadIdx.x) >> 6;
  int lane = threadIdx.x & 63;
  if (n >= N) return;
  int head = lane >> 4;
  int d0 = (lane & 15) * 2;
  unsigned u = Yb[(size_t)n*64 + lane];
  float h0 = bflo(u), h1 = bfhi(u);
  float vs = h0 * asrcw[head*32 + d0] + h1 * asrcw[head*32 + d0 + 1];
  float vd = h0 * adstw[head*32 + d0] + h1 * adstw[head*32 + d0 + 1];
  #pragma unroll
  for (int m = 1; m < 16; m <<= 1){
    vs += __shfl_xor(vs, m, 64);
    vd += __shfl_xor(vd, m, 64);
  }
  if ((lane & 15) == 0){
    a_src[n*4 + head] = vs;
    a_dst[n*4 + head] = vd;
  }
}

// ---------------- edge weights: 16-lane group per node ----------------
__global__ __launch_bounds__(256) void k_edge_w(const int* __restrict__ csr, const int* __restrict__ offs,
                                                const int* __restrict__ deg,
                                                const float4* __restrict__ asrc4, const float4* __restrict__ adst4,
                                                float4* __restrict__ wE, int N){
  int n = blockIdx.x*16 + (threadIdx.x >> 4);
  int l16 = threadIdx.x & 15;
  if (n >= N) return;
  int beg = offs[n], d = deg[n];
  float4 ad = adst4[n];
  for (int i = l16; i < d; i += 16){
    float4 as = asrc4[csr[beg + i]];
    float e0 = as.x + ad.x; e0 = e0 > 0.f ? e0 : 0.2f*e0;
    float e1 = as.y + ad.y; e1 = e1 > 0.f ? e1 : 0.2f*e1;
    float e2 = as.z + ad.z; e2 = e2 > 0.f ? e2 : 0.2f*e2;
    float e3 = as.w + ad.w; e3 = e3 > 0.f ? e3 : 0.2f*e3;
    wE[beg + i] = make_float4(__expf(e0), __expf(e1), __expf(e2), __expf(e3));
  }
}

// ---------------- GAT aggregation: 16 lanes/node, uint4 gathers (4 nodes per wave) ----------------
__global__ __launch_bounds__(256) void k_gat_agg(const uint4* __restrict__ Yb4, const int* __restrict__ csr,
                                                 const int* __restrict__ offs, const int* __restrict__ deg,
                                                 const float* __restrict__ wE, const float* __restrict__ bias,
                                                 float* __restrict__ out, int N){
  int n = blockIdx.x*16 + (threadIdx.x >> 4);
  int l = threadIdx.x & 15;            // 8 channels per lane
  if (n >= N) return;
  int head = l >> 2;
  int beg = offs[n], d = deg[n];
  const int* cp = csr + beg;
  const float* wp = wE + (size_t)beg*4 + head;
  float a[8] = {};
  float sw = 0.f;
  for (int i = 0; i < d; i += 4){
    int j1 = (i+1 < d) ? i+1 : i;
    int j2 = (i+2 < d) ? i+2 : i;
    int j3 = (i+3 < d) ? i+3 : i;
    int n0 = cp[i], n1 = cp[j1], n2 = cp[j2], n3 = cp[j3];
    uint4 v0 = Yb4[(size_t)n0*16 + l];
    uint4 v1 = Yb4[(size_t)n1*16 + l];
    uint4 v2 = Yb4[(size_t)n2*16 + l];
    uint4 v3 = Yb4[(size_t)n3*16 + l];
    float w0 = wp[(size_t)i*4];
    float w1 = (i+1 < d) ? wp[(size_t)j1*4] : 0.f;
    float w2 = (i+2 < d) ? wp[(size_t)j2*4] : 0.f;
    float w3 = (i+3 < d) ? wp[(size_t)j3*4] : 0.f;
    sw += (w0 + w1) + (w2 + w3);
    unsigned u0[4] = {v0.x, v0.y, v0.z, v0.w};
    unsigned u1[4] = {v1.x, v1.y, v1.z, v1.w};
    unsigned u2[4] = {v2.x, v2.y, v2.z, v2.w};
    unsigned u3[4] = {v3.x, v3.y, v3.z, v3.w};
    #pragma unroll
    for (int c = 0; c < 4; ++c){
      a[2*c]   += w0*bflo(u0[c]) + w1*bflo(u1[c]) + w2*bflo(u2[c]) + w3*bflo(u3[c]);
      a[2*c+1] += w0*bfhi(u0[c]) + w1*bfhi(u1[c]) + w2*bfhi(u2[c]) + w3*bfhi(u3[c]);
    }
  }
  float inv = 1.f / sw;
  int c0 = l*8;
  float4 b0 = *(const float4*)(bias + c0);
  float4 b1 = *(const float4*)(bias + c0 + 4);
  float bb8[8] = {b0.x,b0.y,b0.z,b0.w,b1.x,b1.y,b1.z,b1.w};
  float og[8];
  #pragma unroll
  for (int c = 0; c < 8; ++c){
    float z = a[c]*inv + bb8[c];
    og[c] = z > 0.f ? z : expm1f(z);
  }
  float* op = out + (size_t)n*128 + c0;
  *(float4*)op       = make_float4(og[0],og[1],og[2],og[3]);
  *(float4*)(op + 4) = make_float4(og[4],og[5],og[6],og[7]);
}

// ---------------- GCN aggregation + folded BN + ELU + residual: 16 lanes/node, uint4 gathers ----------------
__global__ __launch_bounds__(256) void k_gcn_agg(const uint4* __restrict__ Yb4, const float* __restrict__ resid,
                                                 float* __restrict__ out, const int* __restrict__ csr,
                                                 const int* __restrict__ offs, const int* __restrict__ deg,
                                                 const float* __restrict__ gb, const float* __restrict__ bg,
                                                 const float* __restrict__ bb, const float* __restrict__ bm,
                                                 const float* __restrict__ bv, int N){
  int n = blockIdx.x*16 + (threadIdx.x >> 4);
  int l = threadIdx.x & 15;
  if (n >= N) return;
  int beg = offs[n], d = deg[n];
  const int* cp = csr + beg;
  float a[8] = {};
  for (int i = 0; i < d; i += 4){
    int j1 = (i+1 < d) ? i+1 : i;
    int j2 = (i+2 < d) ? i+2 : i;
    int j3 = (i+3 < d) ? i+3 : i;
    int n0 = cp[i], n1 = cp[j1], n2 = cp[j2], n3 = cp[j3];
    uint4 v0 = Yb4[(size_t)n0*16 + l];
    uint4 v1 = Yb4[(size_t)n1*16 + l];
    uint4 v2 = Yb4[(size_t)n2*16 + l];
    uint4 v3 = Yb4[(size_t)n3*16 + l];
    float m1 = (i+1 < d) ? 1.f : 0.f;
    float m2 = (i+2 < d) ? 1.f : 0.f;
    float m3 = (i+3 < d) ? 1.f : 0.f;
    unsigned u0[4] = {v0.x, v0.y, v0.z, v0.w};
    unsigned u1[4] = {v1.x, v1.y, v1.z, v1.w};
    unsigned u2[4] = {v2.x, v2.y, v2.z, v2.w};
    unsigned u3[4] = {v3.x, v3.y, v3.z, v3.w};
    #pragma unroll
    for (int c = 0; c < 4; ++c){
      a[2*c]   += bflo(u0[c]) + m1*bflo(u1[c]) + m2*bflo(u2[c]) + m3*bflo(u3[c]);
      a[2*c+1] += bfhi(u0[c]) + m1*bfhi(u1[c]) + m2*bfhi(u2[c]) + m3*bfhi(u3[c]);
    }
  }
  float dinv = rsqrtf((float)d);
  int c0 = l*8;
  float4 g0  = *(const float4*)(bg + c0),  g1  = *(const float4*)(bg + c0 + 4);
  float4 bb0 = *(const float4*)(bb + c0),  bb1 = *(const float4*)(bb + c0 + 4);
  float4 m0  = *(const float4*)(bm + c0),  m1v = *(const float4*)(bm + c0 + 4);
  float4 v0  = *(const float4*)(bv + c0),  v1  = *(const float4*)(bv + c0 + 4);
  float4 q0  = *(const float4*)(gb + c0),  q1  = *(const float4*)(gb + c0 + 4);
  float gg[8]  = {g0.x,g0.y,g0.z,g0.w,g1.x,g1.y,g1.z,g1.w};
  float bbb[8] = {bb0.x,bb0.y,bb0.z,bb0.w,bb1.x,bb1.y,bb1.z,bb1.w};
  float mmm[8] = {m0.x,m0.y,m0.z,m0.w,m1v.x,m1v.y,m1v.z,m1v.w};
  float vvv[8] = {v0.x,v0.y,v0.z,v0.w,v1.x,v1.y,v1.z,v1.w};
  float qqq[8] = {q0.x,q0.y,q0.z,q0.w,q1.x,q1.y,q1.z,q1.w};
  float og[8];
  const float* rp = resid ? (resid + (size_t)n*128 + c0) : nullptr;
  float4 r0, r1;
  if (rp){ r0 = *(const float4*)rp; r1 = *(const float4*)(rp + 4); }
  float rr[8];
  if (rp){ rr[0]=r0.x; rr[1]=r0.y; rr[2]=r0.z; rr[3]=r0.w; rr[4]=r1.x; rr[5]=r1.y; rr[6]=r1.z; rr[7]=r1.w; }
  #pragma unroll
  for (int c = 0; c < 8; ++c){
    float As = gg[c] * rsqrtf(vvv[c] + BN_EPS);
    float z = a[c]*dinv*As + (qqq[c] - mmm[c])*As + bbb[c];
    z = z > 0.f ? z : expm1f(z);
    if (rp) z += rr[c];
    og[c] = z;
  }
  float* op = out + (size_t)n*128 + c0;
  *(float4*)op       = make_float4(og[0],og[1],og[2],og[3]);
  *(float4*)(op + 4) = make_float4(og[4],og[5],og[6],og[7]);
}

// ---------------- mean pool per graph (batch sorted) ----------------
__global__ __launch_bounds__(128) void k_pool(const float* __restrict__ H, const int* __restrict__ batch,
                                              float* __restrict__ G, int N){
  int gid = blockIdx.x; int c = threadIdx.x;
  int lo = 0, hi = N;
  while (lo < hi){ int mid = (lo + hi) >> 1; if (batch[mid] < gid) lo = mid + 1; else hi = mid; }
  int start = lo;
  lo = start; hi = N;
  while (lo < hi){ int mid = (lo + hi) >> 1; if (batch[mid] < gid + 1) lo = mid + 1; else hi = mid; }
  int end = lo;
  float acc = 0.f;
  for (int r = start; r < end; ++r) acc += H[(size_t)r*128 + c];
  float cnt = (float)(end - start);
  G[gid*128 + c] = acc / fmaxf(cnt, 1.0f);
}

// ---------------- MLP head ----------------
__global__ __launch_bounds__(128) void k_mlp(const float* __restrict__ G, const float* __restrict__ p1w,
                                             const float* __restrict__ p1b, const float* __restrict__ p2w,
                                             const float* __restrict__ p2b, const float* __restrict__ cw,
                                             const float* __restrict__ cb, float* __restrict__ out, int NG){
  int gid = blockIdx.x; int t = threadIdx.x;
  __shared__ float gv[128], t1[128], e[64];
  gv[t] = G[gid*128 + t];
  __syncthreads();
  float acc = p1b[t];
  for (int k = 0; k < 128; ++k) acc += gv[k] * p1w[k*128 + t];
  t1[t] = acc > 0.f ? acc : expm1f(acc);
  __syncthreads();
  if (t < 64){
    float a = p2b[t];
    for (int k = 0; k < 128; ++k) a += t1[k] * p2w[k*64 + t];
    e[t] = a;
    out[NG*3 + gid*64 + t] = a;
  }
  __syncthreads();
  if (t < 3){
    float a = cb[t];
    for (int k = 0; k < 64; ++k) a += e[k] * cw[k*3 + t];
    out[gid*3 + t] = a;
  }
}

extern "C" void kernel_launch(void* const* d_in, const int* in_sizes, int n_in,
                              void* d_out, int out_size, void* d_ws, size_t ws_size,
                              hipStream_t stream){
  const float* x      = (const float*)d_in[0];
  const int*   ei     = (const int*)d_in[1];
  const int*   batch  = (const int*)d_in[3];
  const float* gat_w  = (const float*)d_in[4];
  const float* att_s  = (const float*)d_in[5];
  const float* att_d  = (const float*)d_in[6];
  const float* gat_b  = (const float*)d_in[7];
  const float* w1 = (const float*)d_in[8];  const float* b1 = (const float*)d_in[9];
  const float* bn1g = (const float*)d_in[10], *bn1b = (const float*)d_in[11],
             * bn1m = (const float*)d_in[12], *bn1v = (const float*)d_in[13];
  const float* w2 = (const float*)d_in[14]; const float* b2 = (const float*)d_in[15];
  const float* bn2g = (const float*)d_in[16], *bn2b = (const float*)d_in[17],
             * bn2m = (const float*)d_in[18], *bn2v = (const float*)d_in[19];
  const float* w3 = (const float*)d_in[20]; const float* b3 = (const float*)d_in[21];
  const float* bn3g = (const float*)d_in[22], *bn3b = (const float*)d_in[23],
             * bn3m = (const float*)d_in[24], *bn3v = (const float*)d_in[25];
  const float* p1w = (const float*)d_in[26]; const float* p1b = (const float*)d_in[27];
  const float* p2w = (const float*)d_in[28]; const float* p2b = (const float*)d_in[29];
  const float* cw  = (const float*)d_in[30]; const float* cb  = (const float*)d_in[31];

  int N  = in_sizes[3];
  int E  = in_sizes[1] / 2;
  int ET = E + N;
  int NG = out_size / 67;

  char* ws = (char*)d_ws;
  size_t off = 0;
  auto alloc = [&](size_t bytes) -> void* {
    void* p = ws + off;
    off = (off + bytes + 255) & ~(size_t)255;
    return p;
  };
  float*    A    = (float*)alloc((size_t)N * 128 * 4);
  float*    Bact = (float*)alloc((size_t)N * 128 * 4);
  u16*      Yb   = (u16*)alloc((size_t)N * 128 * 2);
  int*      csr  = (int*)alloc((size_t)ET * 4);
  int*      deg  = (int*)alloc((size_t)N * 4);
  int*      offs = (int*)alloc((size_t)N * 4);
  int*      curs = (int*)alloc((size_t)N * 4);
  int*      part = (int*)alloc(1024 * 4);
  float*    asrc = (float*)alloc((size_t)N * 4 * 4);
  float*    adst = (float*)alloc((size_t)N * 4 * 4);
  float*    wE   = (float*)alloc((size_t)ET * 4 * 4);
  float*    G    = (float*)alloc((size_t)NG * 128 * 4);
  u16*      WbG  = (u16*)alloc(16384 * 2);
  u16*      Wb1  = (u16*)alloc(16384 * 2);
  u16*      Wb2  = (u16*)alloc(16384 * 2);
  u16*      Wb3  = (u16*)alloc(16384 * 2);

  hipMemsetAsync(deg,  0, (size_t)N * 4, stream);
  hipMemsetAsync(curs, 0, (size_t)N * 4, stream);

  int nb = (N + 1023) / 1024;
  int bpp = (ET + 255)/256;
  k_count<<<8*bpp, 256, 0, stream>>>(ei, E, N, deg);
  k_scan_block<<<nb, 1024, 0, stream>>>(deg, offs, part, N);
  k_scan_part<<<1, 1, 0, stream>>>(part, nb);
  k_add_part<<<(N + 255)/256, 256, 0, stream>>>(offs, part, N);
  k_fill<<<8*bpp, 256, 0, stream>>>(ei, E, N, offs, curs, csr);

  k_wconv<<<64, 256, 0, stream>>>(gat_w, WbG);
  k_wconv<<<64, 256, 0, stream>>>(w1, Wb1);
  k_wconv<<<64, 256, 0, stream>>>(w2, Wb2);
  k_wconv<<<64, 256, 0, stream>>>(w3, Wb3);

  int gblk = (N + 63) / 64;
  int nblk16 = (N + 15) / 16;
  int ablk = (N + 3) / 4;

  // GAT
  k_gemm_mfma<<<gblk, 256, 0, stream>>>(x, WbG, Yb, N, nullptr);
  k_attn<<<ablk, 256, 0, stream>>>((const unsigned*)Yb, att_s, att_d, asrc, adst, N);
  k_edge_w<<<nblk16, 256, 0, stream>>>(csr, offs, deg, (const float4*)asrc, (const float4*)adst,
                                       (float4*)wE, N);
  k_gat_agg<<<nblk16, 256, 0, stream>>>((const uint4*)Yb, csr, offs, deg, wE, gat_b, A, N);

  // GCN 1 (residual A), out Bact
  k_gemm_mfma<<<gblk, 256, 0, stream>>>(A, Wb1, Yb, N, deg);
  k_gcn_agg<<<nblk16, 256, 0, stream>>>((const uint4*)Yb, A, Bact, csr, offs, deg, b1, bn1g, bn1b, bn1m, bn1v, N);
  // GCN 2 (residual Bact), out A
  k_gemm_mfma<<<gblk, 256, 0, stream>>>(Bact, Wb2, Yb, N, deg);
  k_gcn_agg<<<nblk16, 256, 0, stream>>>((const uint4*)Yb, Bact, A, csr, offs, deg, b2, bn2g, bn2b, bn2m, bn2v, N);
  // GCN 3 (no residual), out Bact
  k_gemm_mfma<<<gblk, 256, 0, stream>>>(A, Wb3, Yb, N, deg);
  k_gcn_agg<<<nblk16, 256, 0, stream>>>((const uint4*)Yb, nullptr, Bact, csr, offs, deg, b3, bn3g, bn3b, bn3m, bn3v, N);

  // pool + head
  k_pool<<<NG, 128, 0, stream>>>(Bact, batch, G, N);
  k_mlp<<<NG, 128, 0, stream>>>(G, p1w, p1b, p2w, p2b, cw, cb, (float*)d_out, NG);
}